// Round 1
// baseline (451.269 us; speedup 1.0000x reference)
//
#include <hip/hip_runtime.h>
#include <math.h>

#define B_SZ 2
#define N_PTS 2048
#define DM 128
#define KNN 128
#define NLAYER 4
#define ROWS (B_SZ * N_PTS)
#define EPSLN 1e-5f

// ---------- reductions ----------
__device__ __forceinline__ float waveSum(float v) {
#pragma unroll
  for (int o = 32; o > 0; o >>= 1) v += __shfl_xor(v, o, 64);
  return v;
}
__device__ __forceinline__ float waveMax(float v) {
#pragma unroll
  for (int o = 32; o > 0; o >>= 1) v = fmaxf(v, __shfl_xor(v, o, 64));
  return v;
}
// 128-thread block sum; s2 is __shared__ float[2]; safe for back-to-back calls
__device__ __forceinline__ float blockSum128(float v, float* s2, int t) {
  float w = waveSum(v);
  __syncthreads();
  if ((t & 63) == 0) s2[t >> 6] = w;
  __syncthreads();
  return s2[0] + s2[1];
}

// ---------- 1. knn: radix-select K smallest distances per row ----------
__global__ __launch_bounds__(256) void knn_kernel(const float* __restrict__ xyz,
                                                  int* __restrict__ idx) {
  int row = blockIdx.x;            // 0..ROWS-1
  int b = row >> 11, i = row & (N_PTS - 1);
  const float* xb = xyz + (size_t)b * N_PTS * 3;
  int tid = threadIdx.x;

  __shared__ unsigned int keys[N_PTS];
  __shared__ unsigned int hist[256];
  __shared__ unsigned int scan[256];
  __shared__ unsigned int sh_sel[2];

  float xi = xb[i * 3 + 0], yi = xb[i * 3 + 1], zi = xb[i * 3 + 2];
  float sqi = xi * xi + yi * yi + zi * zi;

  for (int s = 0; s < 8; ++s) {
    int j = tid * 8 + s;
    float xj = xb[j * 3 + 0], yj = xb[j * 3 + 1], zj = xb[j * 3 + 2];
    float sqj = xj * xj + yj * yj + zj * zj;
    float dt = xi * xj + yi * yj + zi * zj;
    float d = sqi + sqj - 2.0f * dt;
    unsigned int u = __float_as_uint(d);
    u = (u & 0x80000000u) ? ~u : (u | 0x80000000u);  // monotone key
    keys[j] = u;
  }
  __syncthreads();

  unsigned int prefix = 0;
  int need = KNN;
  for (int shift = 24; shift >= 0; shift -= 8) {
    hist[tid] = 0;
    __syncthreads();
    for (int s = 0; s < 8; ++s) {
      unsigned int k = keys[tid * 8 + s];
      bool m = (shift == 24) || ((k >> (shift + 8)) == prefix);
      if (m) atomicAdd(&hist[(k >> shift) & 255u], 1u);
    }
    __syncthreads();
    if (tid == 0) {
      unsigned int c = 0, dsel = 0;
      int nd = need;
      for (int d2 = 0; d2 < 256; ++d2) {
        unsigned int h = hist[d2];
        if (c + h >= (unsigned int)nd) { dsel = d2; nd = nd - (int)c; break; }
        c += h;
      }
      sh_sel[0] = dsel; sh_sel[1] = (unsigned int)nd;
    }
    __syncthreads();
    prefix = (prefix << 8) | sh_sel[0];
    need = (int)sh_sel[1];
    __syncthreads();
  }
  unsigned int T = prefix;
  int need_eq = need;

  int cnt_lt = 0, cnt_eq = 0;
  for (int s = 0; s < 8; ++s) {
    unsigned int k = keys[tid * 8 + s];
    cnt_lt += (k < T);
    cnt_eq += (k == T);
  }
  unsigned int packed = (unsigned int)cnt_lt | ((unsigned int)cnt_eq << 16);
  scan[tid] = packed;
  __syncthreads();
  for (int off = 1; off < 256; off <<= 1) {
    unsigned int v = scan[tid];
    unsigned int add = (tid >= off) ? scan[tid - off] : 0u;
    __syncthreads();
    scan[tid] = v + add;
    __syncthreads();
  }
  unsigned int incl = scan[tid];
  unsigned int tot = scan[255];
  unsigned int excl = incl - packed;
  int lt_base = (int)(excl & 0xFFFFu);
  int eq_base = (int)(excl >> 16);
  int total_lt = (int)(tot & 0xFFFFu);

  int* orow = idx + (size_t)row * KNN;
  int lpos = 0, epos = 0;
  for (int s = 0; s < 8; ++s) {
    int j = tid * 8 + s;
    unsigned int k = keys[j];
    if (k < T) {
      orow[lt_base + lpos] = j; lpos++;
    } else if (k == T) {
      int r = eq_base + epos; epos++;
      if (r < need_eq) orow[total_lt + r] = j;
    }
  }
}

// ---------- 2. per-layer weight rowsums ----------
__global__ __launch_bounds__(128) void rowsum_kernel(
    const float* __restrict__ Wq, const float* __restrict__ bq,
    const float* __restrict__ Wk, const float* __restrict__ bk,
    const float* __restrict__ Wp2, const float* __restrict__ bp2,
    float* __restrict__ rs, float* __restrict__ ssum) {
  int l = blockIdx.x, d = threadIdx.x;
  __shared__ float s2[2];
  const float* wq = Wq + (size_t)l * DM * DM;
  const float* wk = Wk + (size_t)l * DM * DM;
  const float* wp2 = Wp2 + (size_t)l * DM * DM;
  float a = 0.f, b = 0.f, c = 0.f;
  for (int j = 0; j < DM; ++j) {
    a += wq[d * DM + j];
    b += wk[d * DM + j];
    c += wp2[d * DM + j];
  }
  rs[l * 3 * DM + d] = a;
  rs[l * 3 * DM + DM + d] = b;
  rs[l * 3 * DM + 2 * DM + d] = c;
  float sq = blockSum128(bq[l * DM + d], s2, d);
  float sk = blockSum128(bk[l * DM + d], s2, d);
  float sp = blockSum128(bp2[l * DM + d], s2, d);
  if (d == 0) { ssum[l * 4 + 0] = sq; ssum[l * 4 + 1] = sk; ssum[l * 4 + 2] = sp; }
}

// ---------- 3. per-layer V projection + q/k scalar sums ----------
__global__ __launch_bounds__(128) void vqk_kernel(
    const float* __restrict__ feat, const float* __restrict__ Wv,
    const float* __restrict__ bv, const float* __restrict__ rs,
    const float* __restrict__ ssum, float* __restrict__ Vf,
    float* __restrict__ qsum, float* __restrict__ ksum) {
  int n = blockIdx.x, d = threadIdx.x;
  __shared__ float fr[DM];
  __shared__ float s2[2];
  fr[d] = feat[(size_t)n * DM + d];
  __syncthreads();
  float acc = 0.f;
#pragma unroll 4
  for (int j = 0; j < DM; ++j) acc = fmaf(fr[j], Wv[j * DM + d], acc);
  Vf[(size_t)n * DM + d] = acc + bv[d];
  float q = blockSum128(fr[d] * rs[d], s2, d);
  float k = blockSum128(fr[d] * rs[DM + d], s2, d);
  if (d == 0) { qsum[n] = q + ssum[0]; ksum[n] = k + ssum[1]; }
}

// ---------- 4. attention: logits+softmax (pass1), aggregate (pass2) ----------
__global__ __launch_bounds__(128) void attn_kernel(
    const float* __restrict__ xyz, const int* __restrict__ idx,
    const float* __restrict__ Vf, const float* __restrict__ qsum,
    const float* __restrict__ ksum, const float* __restrict__ Wp1,
    const float* __restrict__ bp1, const float* __restrict__ rs,
    const float* __restrict__ ssum, float* __restrict__ hagg,
    float* __restrict__ vagg) {
  int row = blockIdx.x;
  int b = row >> 11;
  int i = row & (N_PTS - 1);
  int t = threadIdx.x;  // 0..127

  __shared__ float4 w1p[DM];     // (Wp1[0,d], Wp1[1,d], Wp1[2,d], bp1[d])
  __shared__ float w2rs[DM];
  __shared__ float rel[KNN][3];
  __shared__ int jrow[KNN];
  __shared__ float attnv[KNN];
  __shared__ float sredA[2];
  __shared__ float sredB[2];

  w1p[t] = make_float4(Wp1[t], Wp1[DM + t], Wp1[2 * DM + t], bp1[t]);
  w2rs[t] = rs[2 * DM + t];

  const float* xb = xyz + (size_t)b * N_PTS * 3;
  float xi = xb[i * 3 + 0], yi = xb[i * 3 + 1], zi = xb[i * 3 + 2];
  int j = idx[(size_t)row * KNN + t];
  jrow[t] = j;
  float rx = xi - xb[j * 3 + 0];
  float ry = yi - xb[j * 3 + 1];
  float rz = zi - xb[j * 3 + 2];
  rel[t][0] = rx; rel[t][1] = ry; rel[t][2] = rz;
  __syncthreads();

  // pass1: thread t handles neighbor t
  float acc = 0.f;
#pragma unroll 4
  for (int d = 0; d < DM; ++d) {
    float4 w = w1p[d];
    float h = fmaf(rx, w.x, fmaf(ry, w.y, fmaf(rz, w.z, w.w)));
    h = fmaxf(h, 0.f);
    acc = fmaf(h, w2rs[d], acc);
  }
  float logit = qsum[row] - ksum[b * N_PTS + j] + acc + ssum[2];

  // softmax over 128 threads
  float m = waveMax(logit);
  if ((t & 63) == 0) sredA[t >> 6] = m;
  __syncthreads();
  m = fmaxf(sredA[0], sredA[1]);
  float e = __expf(logit - m);
  float sw = waveSum(e);
  if ((t & 63) == 0) sredB[t >> 6] = sw;
  __syncthreads();
  float ssm = sredB[0] + sredB[1];
  attnv[t] = e / ssm;
  __syncthreads();

  // pass2: thread t = output dim d
  float4 wd = w1p[t];
  float ha = 0.f, va = 0.f;
#pragma unroll 2
  for (int k = 0; k < KNN; ++k) {
    float a = attnv[k];
    float h = fmaf(rel[k][0], wd.x, fmaf(rel[k][1], wd.y, fmaf(rel[k][2], wd.z, wd.w)));
    h = fmaxf(h, 0.f);
    ha = fmaf(a, h, ha);
    va = fmaf(a, Vf[((size_t)(b * N_PTS) + jrow[k]) * DM + t], va);
  }
  hagg[(size_t)row * DM + t] = ha;
  vagg[(size_t)row * DM + t] = va;
}

// ---------- 5. layer output: feat + gamma*((vagg + hagg@Wp2 + bp2)@Wproj + bproj) ----------
__global__ __launch_bounds__(128) void layerout_kernel(
    const float* __restrict__ feat_in, const float* __restrict__ hagg,
    const float* __restrict__ vagg, const float* __restrict__ Wp2,
    const float* __restrict__ bp2, const float* __restrict__ Wproj,
    const float* __restrict__ bproj, const float* __restrict__ gamma, int l,
    float* __restrict__ feat_out) {
  int n = blockIdx.x, d = threadIdx.x;
  __shared__ float hrow[DM];
  __shared__ float z[DM];
  hrow[d] = hagg[(size_t)n * DM + d];
  __syncthreads();
  float acc = 0.f;
#pragma unroll 4
  for (int j = 0; j < DM; ++j) acc = fmaf(hrow[j], Wp2[j * DM + d], acc);
  z[d] = vagg[(size_t)n * DM + d] + acc + bp2[d];
  __syncthreads();
  float acc2 = 0.f;
#pragma unroll 4
  for (int j = 0; j < DM; ++j) acc2 = fmaf(z[j], Wproj[j * DM + d], acc2);
  float g = gamma[l];
  feat_out[(size_t)n * DM + d] =
      feat_in[(size_t)n * DM + d] + g * (acc2 + bproj[d]);
}

// ---------- 6. timestep embedding MLP ----------
__global__ __launch_bounds__(128) void temb_kernel(
    const int* __restrict__ t, const float* __restrict__ tW1,
    const float* __restrict__ tb1, const float* __restrict__ tW2,
    const float* __restrict__ tb2, float* __restrict__ temb) {
  int b = blockIdx.x, d = threadIdx.x;
  __shared__ float emb[DM];
  __shared__ float h1[DM];
  float tv = (float)t[b];
  float lg = logf(10000.0f);
  if (d < 64) {
    float f = expf(-lg * (float)d / 63.0f);
    emb[d] = sinf(tv * f);
  } else {
    float f = expf(-lg * (float)(d - 64) / 63.0f);
    emb[d] = cosf(tv * f);
  }
  __syncthreads();
  float acc = tb1[d];
  for (int j = 0; j < DM; ++j) acc = fmaf(emb[j], tW1[j * DM + d], acc);
  h1[d] = fmaxf(acc, 0.f);
  __syncthreads();
  float acc2 = tb2[d];
  for (int j = 0; j < DM; ++j) acc2 = fmaf(h1[j], tW2[j * DM + d], acc2);
  temb[b * DM + d] = acc2;
}

// ---------- 7. DDPM head ----------
__global__ __launch_bounds__(128) void head_kernel(
    const float* __restrict__ x_t, const float* __restrict__ fused,
    const float* __restrict__ temb, const float* __restrict__ nW1,
    const float* __restrict__ nb1, const float* __restrict__ ng1,
    const float* __restrict__ nbe1, const float* __restrict__ nW2,
    const float* __restrict__ nb2, const float* __restrict__ ng2,
    const float* __restrict__ nbe2, const float* __restrict__ nW3,
    const float* __restrict__ nb3, float* __restrict__ out) {
  int row = blockIdx.x;
  int b = row >> 11;
  int d = threadIdx.x;
  __shared__ float h0[259];
  __shared__ float h[DM];
  __shared__ float s2[2];
  if (d < 3) h0[d] = x_t[(size_t)row * 3 + d];
  h0[3 + d] = fused[(size_t)row * DM + d];
  h0[131 + d] = temb[b * DM + d];
  __syncthreads();

  float acc = nb1[d];
  for (int j = 0; j < 259; ++j) acc = fmaf(h0[j], nW1[j * DM + d], acc);
  float m = blockSum128(acc, s2, d) * (1.0f / 128.0f);
  float c = acc - m;
  float var = blockSum128(c * c, s2, d) * (1.0f / 128.0f);
  float y = c * rsqrtf(var + EPSLN) * ng1[d] + nbe1[d];
  y = fmaxf(y, 0.f);
  h[d] = y;
  __syncthreads();

  float acc2 = nb2[d];
#pragma unroll 4
  for (int j = 0; j < DM; ++j) acc2 = fmaf(h[j], nW2[j * DM + d], acc2);
  float m2 = blockSum128(acc2, s2, d) * (1.0f / 128.0f);
  float c2 = acc2 - m2;
  float var2 = blockSum128(c2 * c2, s2, d) * (1.0f / 128.0f);
  float y2 = c2 * rsqrtf(var2 + EPSLN) * ng2[d] + nbe2[d];
  y2 = fmaxf(y2, 0.f);

  float r0 = blockSum128(y2 * nW3[d * 3 + 0], s2, d);
  float r1 = blockSum128(y2 * nW3[d * 3 + 1], s2, d);
  float r2 = blockSum128(y2 * nW3[d * 3 + 2], s2, d);
  if (d == 0) {
    out[(size_t)row * 3 + 0] = r0 + nb3[0];
    out[(size_t)row * 3 + 1] = r1 + nb3[1];
    out[(size_t)row * 3 + 2] = r2 + nb3[2];
  }
}

// ---------- launch ----------
extern "C" void kernel_launch(void* const* d_in, const int* in_sizes, int n_in,
                              void* d_out, int out_size, void* d_ws,
                              size_t ws_size, hipStream_t stream) {
  const float* xyz = (const float*)d_in[0];
  const float* feat = (const float*)d_in[1];
  const float* x_t = (const float*)d_in[2];
  const int* t = (const int*)d_in[3];
  const float* Wq = (const float*)d_in[4];
  const float* bq = (const float*)d_in[5];
  const float* Wk = (const float*)d_in[6];
  const float* bk = (const float*)d_in[7];
  const float* Wv = (const float*)d_in[8];
  const float* bv = (const float*)d_in[9];
  const float* Wp1 = (const float*)d_in[10];
  const float* bp1 = (const float*)d_in[11];
  const float* Wp2 = (const float*)d_in[12];
  const float* bp2 = (const float*)d_in[13];
  const float* gamma = (const float*)d_in[14];
  const float* Wproj = (const float*)d_in[15];
  const float* bproj = (const float*)d_in[16];
  const float* tW1 = (const float*)d_in[17];
  const float* tb1 = (const float*)d_in[18];
  const float* tW2 = (const float*)d_in[19];
  const float* tb2 = (const float*)d_in[20];
  const float* nW1 = (const float*)d_in[21];
  const float* nb1 = (const float*)d_in[22];
  const float* ng1 = (const float*)d_in[23];
  const float* nbe1 = (const float*)d_in[24];
  const float* nW2 = (const float*)d_in[25];
  const float* nb2 = (const float*)d_in[26];
  const float* ng2 = (const float*)d_in[27];
  const float* nbe2 = (const float*)d_in[28];
  const float* nW3 = (const float*)d_in[29];
  const float* nb3 = (const float*)d_in[30];
  float* out = (float*)d_out;

  char* ws = (char*)d_ws;
  size_t off = 0;
  int* w_idx = (int*)(ws + off); off += (size_t)ROWS * KNN * 4;
  float* w_Vf = (float*)(ws + off); off += (size_t)ROWS * DM * 4;
  float* w_qsum = (float*)(ws + off); off += (size_t)ROWS * 4;
  float* w_ksum = (float*)(ws + off); off += (size_t)ROWS * 4;
  float* w_hagg = (float*)(ws + off); off += (size_t)ROWS * DM * 4;
  float* w_vagg = (float*)(ws + off); off += (size_t)ROWS * DM * 4;
  float* w_fA = (float*)(ws + off); off += (size_t)ROWS * DM * 4;
  float* w_fB = (float*)(ws + off); off += (size_t)ROWS * DM * 4;
  float* w_temb = (float*)(ws + off); off += (size_t)B_SZ * DM * 4;
  float* w_rs = (float*)(ws + off); off += (size_t)NLAYER * 3 * DM * 4;
  float* w_ssum = (float*)(ws + off); off += (size_t)NLAYER * 4 * 4;

  knn_kernel<<<ROWS, 256, 0, stream>>>(xyz, w_idx);
  rowsum_kernel<<<NLAYER, DM, 0, stream>>>(Wq, bq, Wk, bk, Wp2, bp2, w_rs, w_ssum);

  const float* fin = feat;
  float* fout = w_fA;
  for (int l = 0; l < NLAYER; ++l) {
    const float* rsL = w_rs + (size_t)l * 3 * DM;
    const float* ssL = w_ssum + (size_t)l * 4;
    vqk_kernel<<<ROWS, DM, 0, stream>>>(fin, Wv + (size_t)l * DM * DM,
                                        bv + (size_t)l * DM, rsL, ssL, w_Vf,
                                        w_qsum, w_ksum);
    attn_kernel<<<ROWS, DM, 0, stream>>>(
        xyz, w_idx, w_Vf, w_qsum, w_ksum, Wp1 + (size_t)l * 3 * DM,
        bp1 + (size_t)l * DM, rsL, ssL, w_hagg, w_vagg);
    layerout_kernel<<<ROWS, DM, 0, stream>>>(
        fin, w_hagg, w_vagg, Wp2 + (size_t)l * DM * DM, bp2 + (size_t)l * DM,
        Wproj + (size_t)l * DM * DM, bproj + (size_t)l * DM, gamma, l, fout);
    fin = fout;
    fout = (fout == w_fA) ? w_fB : w_fA;
  }

  temb_kernel<<<B_SZ, DM, 0, stream>>>(t, tW1, tb1, tW2, tb2, w_temb);
  head_kernel<<<ROWS, DM, 0, stream>>>(x_t, fin, w_temb, nW1, nb1, ng1, nbe1,
                                       nW2, nb2, ng2, nbe2, nW3, nb3, out);
}

// Round 2
// 346.132 us; speedup vs baseline: 1.3037x; 1.3037x over previous
//
#include <hip/hip_runtime.h>
#include <math.h>

#define B_SZ 2
#define N_PTS 2048
#define DM 128
#define KNN 128
#define NLAYER 4
#define ROWS (B_SZ * N_PTS)
#define RB 8
#define EPSLN 1e-5f

// ---------- reductions ----------
__device__ __forceinline__ float waveSum(float v) {
#pragma unroll
  for (int o = 32; o > 0; o >>= 1) v += __shfl_xor(v, o, 64);
  return v;
}
__device__ __forceinline__ float waveMax(float v) {
#pragma unroll
  for (int o = 32; o > 0; o >>= 1) v = fmaxf(v, __shfl_xor(v, o, 64));
  return v;
}
__device__ __forceinline__ float blockSum128(float v, float* s2, int t) {
  float w = waveSum(v);
  __syncthreads();
  if ((t & 63) == 0) s2[t >> 6] = w;
  __syncthreads();
  return s2[0] + s2[1];
}
__device__ __forceinline__ unsigned waveScanIncl(unsigned v, int lane) {
#pragma unroll
  for (int o = 1; o < 64; o <<= 1) {
    unsigned u = (unsigned)__shfl_up((int)v, o, 64);
    if (lane >= o) v += u;
  }
  return v;
}

// ---------- 1. knn: radix-select K smallest, keys in registers ----------
__global__ __launch_bounds__(256) void knn_kernel(const float* __restrict__ xyz,
                                                  int* __restrict__ idx) {
  int row = blockIdx.x;
  int b = row >> 11, i = row & (N_PTS - 1);
  const float* xb = xyz + (size_t)b * N_PTS * 3;
  int tid = threadIdx.x;
  int lane = tid & 63, wid = tid >> 6;

  __shared__ unsigned hist[256];
  __shared__ unsigned wred[4];
  __shared__ unsigned sel[2];

  float xi = xb[i * 3 + 0], yi = xb[i * 3 + 1], zi = xb[i * 3 + 2];
  float sqi = xi * xi + yi * yi + zi * zi;

  // vectorized load of this thread's 8 candidate points (24 floats = 6 float4)
  float p[24];
  {
    const float4* xb4 = (const float4*)xb;
#pragma unroll
    for (int q = 0; q < 6; ++q) {
      float4 v = xb4[tid * 6 + q];
      p[q * 4 + 0] = v.x; p[q * 4 + 1] = v.y; p[q * 4 + 2] = v.z; p[q * 4 + 3] = v.w;
    }
  }
  unsigned key[8];
#pragma unroll
  for (int s = 0; s < 8; ++s) {
    float xj = p[s * 3 + 0], yj = p[s * 3 + 1], zj = p[s * 3 + 2];
    float d = sqi + xj * xj + yj * yj + zj * zj -
              2.0f * (xi * xj + yi * yj + zi * zj);
    unsigned u = __float_as_uint(d);
    key[s] = (u & 0x80000000u) ? ~u : (u | 0x80000000u);
  }

  unsigned prefix = 0;
  unsigned need = KNN;
  for (int shift = 24; shift >= 0; shift -= 8) {
    hist[tid] = 0;
    __syncthreads();
    if (shift == 24) {
      // all keys active; exponent bytes are heavily clustered -> ballot-aggregate
#pragma unroll
      for (int s = 0; s < 8; ++s) {
        unsigned bin = key[s] >> 24;
        unsigned long long act = __ballot(1);
        while (act) {
          int src = __builtin_ctzll(act);
          unsigned bsel = (unsigned)__shfl((int)bin, src, 64);
          unsigned long long grp = __ballot(bin == bsel);
          if (lane == src)
            atomicAdd(&hist[bsel], (unsigned)__builtin_popcountll(grp));
          act &= ~grp;
        }
      }
    } else {
#pragma unroll
      for (int s = 0; s < 8; ++s) {
        unsigned k = key[s];
        if ((k >> (shift + 8)) == prefix)
          atomicAdd(&hist[(k >> shift) & 255u], 1u);
      }
    }
    __syncthreads();
    unsigned h = hist[tid];
    unsigned incl = waveScanIncl(h, lane);
    if (lane == 63) wred[wid] = incl;
    __syncthreads();
    unsigned offs = 0;
    for (int w = 0; w < wid; ++w) offs += wred[w];
    incl += offs;
    unsigned excl = incl - h;
    if (excl < need && need <= incl) { sel[0] = (unsigned)tid; sel[1] = need - excl; }
    __syncthreads();
    prefix = (prefix << 8) | sel[0];
    need = sel[1];
  }
  unsigned T = prefix;
  int need_eq = (int)need;

  unsigned clt = 0, ceq = 0;
#pragma unroll
  for (int s = 0; s < 8; ++s) {
    clt += (key[s] < T);
    ceq += (key[s] == T);
  }
  unsigned packed = clt | (ceq << 16);
  unsigned incl = waveScanIncl(packed, lane);
  if (lane == 63) wred[wid] = incl;
  __syncthreads();
  unsigned offs = 0;
  for (int w = 0; w < wid; ++w) offs += wred[w];
  unsigned totAll = wred[0] + wred[1] + wred[2] + wred[3];
  incl += offs;
  unsigned excl = incl - packed;
  int lt_base = (int)(excl & 0xFFFFu);
  int eq_base = (int)(excl >> 16);
  int total_lt = (int)(totAll & 0xFFFFu);

  int* orow = idx + (size_t)row * KNN;
  int lpos = 0, epos = 0;
#pragma unroll
  for (int s = 0; s < 8; ++s) {
    int j = tid * 8 + s;
    unsigned k = key[s];
    if (k < T) {
      orow[lt_base + lpos] = j; lpos++;
    } else if (k == T) {
      int r = eq_base + epos; epos++;
      if (r < need_eq) orow[total_lt + r] = j;
    }
  }
}

// ---------- 2. per-layer weight rowsums ----------
__global__ __launch_bounds__(128) void rowsum_kernel(
    const float* __restrict__ Wq, const float* __restrict__ bq,
    const float* __restrict__ Wk, const float* __restrict__ bk,
    const float* __restrict__ Wp2, const float* __restrict__ bp2,
    float* __restrict__ rs, float* __restrict__ ssum) {
  int l = blockIdx.x, d = threadIdx.x;
  __shared__ float s2[2];
  const float* wq = Wq + (size_t)l * DM * DM;
  const float* wk = Wk + (size_t)l * DM * DM;
  const float* wp2 = Wp2 + (size_t)l * DM * DM;
  float a = 0.f, b = 0.f, c = 0.f;
  for (int j = 0; j < DM; ++j) {
    a += wq[d * DM + j];
    b += wk[d * DM + j];
    c += wp2[d * DM + j];
  }
  rs[l * 3 * DM + d] = a;
  rs[l * 3 * DM + DM + d] = b;
  rs[l * 3 * DM + 2 * DM + d] = c;
  float sq = blockSum128(bq[l * DM + d], s2, d);
  float sk = blockSum128(bk[l * DM + d], s2, d);
  float sp = blockSum128(bp2[l * DM + d], s2, d);
  if (d == 0) { ssum[l * 4 + 0] = sq; ssum[l * 4 + 1] = sk; ssum[l * 4 + 2] = sp; }
}

// ---------- 3. V projection + q/k sums, 8 rows/block ----------
__global__ __launch_bounds__(128) void vqk_kernel(
    const float* __restrict__ feat, const float* __restrict__ Wv,
    const float* __restrict__ bv, const float* __restrict__ rs,
    const float* __restrict__ ssum, float* __restrict__ Vf,
    float* __restrict__ qsum, float* __restrict__ ksum) {
  int n0 = blockIdx.x * RB;
  int d = threadIdx.x;
  int lane = d & 63, wid = d >> 6;
  __shared__ float fr[RB][DM];
  __shared__ float s4[4];
#pragma unroll
  for (int r = 0; r < RB; ++r) fr[r][d] = feat[(size_t)(n0 + r) * DM + d];
  __syncthreads();
  float acc[RB];
#pragma unroll
  for (int r = 0; r < RB; ++r) acc[r] = 0.f;
  for (int j = 0; j < DM; j += 4) {
    float w0 = Wv[(j + 0) * DM + d], w1 = Wv[(j + 1) * DM + d];
    float w2 = Wv[(j + 2) * DM + d], w3 = Wv[(j + 3) * DM + d];
#pragma unroll
    for (int r = 0; r < RB; ++r) {
      float4 f = *(const float4*)&fr[r][j];
      acc[r] = fmaf(f.x, w0, fmaf(f.y, w1, fmaf(f.z, w2, fmaf(f.w, w3, acc[r]))));
    }
  }
  float bvd = bv[d];
#pragma unroll
  for (int r = 0; r < RB; ++r) Vf[(size_t)(n0 + r) * DM + d] = acc[r] + bvd;

  float rsq = rs[d], rsk = rs[DM + d];
  float s0 = ssum[0], s1v = ssum[1];
#pragma unroll
  for (int r = 0; r < RB; ++r) {
    float f = fr[r][d];
    float a = waveSum(f * rsq);
    float k = waveSum(f * rsk);
    if (lane == 0) { s4[wid * 2] = a; s4[wid * 2 + 1] = k; }
    __syncthreads();
    if (d == 0) {
      qsum[n0 + r] = s4[0] + s4[2] + s0;
      ksum[n0 + r] = s4[1] + s4[3] + s1v;
    }
    __syncthreads();
  }
}

// ---------- 4. attention ----------
__global__ __launch_bounds__(128) void attn_kernel(
    const float* __restrict__ xyz, const int* __restrict__ idx,
    const float* __restrict__ Vf, const float* __restrict__ qsum,
    const float* __restrict__ ksum, const float* __restrict__ Wp1,
    const float* __restrict__ bp1, const float* __restrict__ rs,
    const float* __restrict__ ssum, float* __restrict__ hagg,
    float* __restrict__ vagg) {
  int row = blockIdx.x;
  int b = row >> 11;
  int i = row & (N_PTS - 1);
  int t = threadIdx.x;

  __shared__ float4 w1p[DM];
  __shared__ float w2rs[DM];
  __shared__ float4 rel4[KNN];
  __shared__ int jrow[KNN];
  __shared__ float attnv[KNN];
  __shared__ float sredA[2];
  __shared__ float sredB[2];

  w1p[t] = make_float4(Wp1[t], Wp1[DM + t], Wp1[2 * DM + t], bp1[t]);
  w2rs[t] = rs[2 * DM + t];

  const float* xb = xyz + (size_t)b * N_PTS * 3;
  float xi = xb[i * 3 + 0], yi = xb[i * 3 + 1], zi = xb[i * 3 + 2];
  int j = idx[(size_t)row * KNN + t];
  jrow[t] = j;
  float rx = xi - xb[j * 3 + 0];
  float ry = yi - xb[j * 3 + 1];
  float rz = zi - xb[j * 3 + 2];
  rel4[t] = make_float4(rx, ry, rz, 0.f);
  __syncthreads();

  float acc = 0.f;
#pragma unroll 4
  for (int d = 0; d < DM; ++d) {
    float4 w = w1p[d];
    float h = fmaf(rx, w.x, fmaf(ry, w.y, fmaf(rz, w.z, w.w)));
    h = fmaxf(h, 0.f);
    acc = fmaf(h, w2rs[d], acc);
  }
  float logit = qsum[row] - ksum[b * N_PTS + j] + acc + ssum[2];

  float m = waveMax(logit);
  if ((t & 63) == 0) sredA[t >> 6] = m;
  __syncthreads();
  m = fmaxf(sredA[0], sredA[1]);
  float e = __expf(logit - m);
  float sw = waveSum(e);
  if ((t & 63) == 0) sredB[t >> 6] = sw;
  __syncthreads();
  float ssm = sredB[0] + sredB[1];
  attnv[t] = e / ssm;
  __syncthreads();

  float4 wd = w1p[t];
  float ha = 0.f, va = 0.f;
#pragma unroll 2
  for (int k = 0; k < KNN; ++k) {
    float a = attnv[k];
    float4 rl = rel4[k];
    float h = fmaf(rl.x, wd.x, fmaf(rl.y, wd.y, fmaf(rl.z, wd.z, wd.w)));
    h = fmaxf(h, 0.f);
    ha = fmaf(a, h, ha);
    va = fmaf(a, Vf[((size_t)(b * N_PTS) + jrow[k]) * DM + t], va);
  }
  hagg[(size_t)row * DM + t] = ha;
  vagg[(size_t)row * DM + t] = va;
}

// ---------- 5. layer output, 8 rows/block ----------
__global__ __launch_bounds__(128) void layerout_kernel(
    const float* __restrict__ feat_in, const float* __restrict__ hagg,
    const float* __restrict__ vagg, const float* __restrict__ Wp2,
    const float* __restrict__ bp2, const float* __restrict__ Wproj,
    const float* __restrict__ bproj, const float* __restrict__ gamma, int l,
    float* __restrict__ feat_out) {
  int n0 = blockIdx.x * RB;
  int d = threadIdx.x;
  __shared__ float hrow[RB][DM];
  __shared__ float z[RB][DM];
#pragma unroll
  for (int r = 0; r < RB; ++r) hrow[r][d] = hagg[(size_t)(n0 + r) * DM + d];
  __syncthreads();
  float acc[RB];
#pragma unroll
  for (int r = 0; r < RB; ++r) acc[r] = 0.f;
  for (int j = 0; j < DM; j += 4) {
    float w0 = Wp2[(j + 0) * DM + d], w1 = Wp2[(j + 1) * DM + d];
    float w2 = Wp2[(j + 2) * DM + d], w3 = Wp2[(j + 3) * DM + d];
#pragma unroll
    for (int r = 0; r < RB; ++r) {
      float4 f = *(const float4*)&hrow[r][j];
      acc[r] = fmaf(f.x, w0, fmaf(f.y, w1, fmaf(f.z, w2, fmaf(f.w, w3, acc[r]))));
    }
  }
  float bpd = bp2[d];
#pragma unroll
  for (int r = 0; r < RB; ++r)
    z[r][d] = vagg[(size_t)(n0 + r) * DM + d] + acc[r] + bpd;
  __syncthreads();
  float acc2[RB];
#pragma unroll
  for (int r = 0; r < RB; ++r) acc2[r] = 0.f;
  for (int j = 0; j < DM; j += 4) {
    float w0 = Wproj[(j + 0) * DM + d], w1 = Wproj[(j + 1) * DM + d];
    float w2 = Wproj[(j + 2) * DM + d], w3 = Wproj[(j + 3) * DM + d];
#pragma unroll
    for (int r = 0; r < RB; ++r) {
      float4 f = *(const float4*)&z[r][j];
      acc2[r] = fmaf(f.x, w0, fmaf(f.y, w1, fmaf(f.z, w2, fmaf(f.w, w3, acc2[r]))));
    }
  }
  float g = gamma[l];
  float bpr = bproj[d];
#pragma unroll
  for (int r = 0; r < RB; ++r)
    feat_out[(size_t)(n0 + r) * DM + d] =
        feat_in[(size_t)(n0 + r) * DM + d] + g * (acc2[r] + bpr);
}

// ---------- 6. timestep embedding MLP ----------
__global__ __launch_bounds__(128) void temb_kernel(
    const int* __restrict__ t, const float* __restrict__ tW1,
    const float* __restrict__ tb1, const float* __restrict__ tW2,
    const float* __restrict__ tb2, float* __restrict__ temb) {
  int b = blockIdx.x, d = threadIdx.x;
  __shared__ float emb[DM];
  __shared__ float h1[DM];
  float tv = (float)t[b];
  float lg = logf(10000.0f);
  if (d < 64) {
    float f = expf(-lg * (float)d / 63.0f);
    emb[d] = sinf(tv * f);
  } else {
    float f = expf(-lg * (float)(d - 64) / 63.0f);
    emb[d] = cosf(tv * f);
  }
  __syncthreads();
  float acc = tb1[d];
  for (int j = 0; j < DM; ++j) acc = fmaf(emb[j], tW1[j * DM + d], acc);
  h1[d] = fmaxf(acc, 0.f);
  __syncthreads();
  float acc2 = tb2[d];
  for (int j = 0; j < DM; ++j) acc2 = fmaf(h1[j], tW2[j * DM + d], acc2);
  temb[b * DM + d] = acc2;
}

// ---------- 7. DDPM head, 8 rows/block ----------
__global__ __launch_bounds__(128) void head_kernel(
    const float* __restrict__ x_t, const float* __restrict__ fused,
    const float* __restrict__ temb, const float* __restrict__ nW1,
    const float* __restrict__ nb1, const float* __restrict__ ng1,
    const float* __restrict__ nbe1, const float* __restrict__ nW2,
    const float* __restrict__ nb2, const float* __restrict__ ng2,
    const float* __restrict__ nbe2, const float* __restrict__ nW3,
    const float* __restrict__ nb3, float* __restrict__ out) {
  int n0 = blockIdx.x * RB;
  int d = threadIdx.x;
  int lane = d & 63, wid = d >> 6;
  __shared__ float h0[RB][260];
  __shared__ float hh[RB][DM];
  __shared__ float s6[6];

#pragma unroll
  for (int r = 0; r < RB; ++r) {
    int row = n0 + r;
    int b = row >> 11;
    h0[r][3 + d] = fused[(size_t)row * DM + d];
    h0[r][131 + d] = temb[b * DM + d];
    if (d < 3) h0[r][d] = x_t[(size_t)row * 3 + d];
    if (d == 0) h0[r][259] = 0.f;
  }
  __syncthreads();

  float acc[RB];
#pragma unroll
  for (int r = 0; r < RB; ++r) acc[r] = nb1[d];
  for (int j = 0; j < 256; j += 4) {
    float w0 = nW1[(j + 0) * DM + d], w1 = nW1[(j + 1) * DM + d];
    float w2 = nW1[(j + 2) * DM + d], w3 = nW1[(j + 3) * DM + d];
#pragma unroll
    for (int r = 0; r < RB; ++r) {
      float4 f = *(const float4*)&h0[r][j];
      acc[r] = fmaf(f.x, w0, fmaf(f.y, w1, fmaf(f.z, w2, fmaf(f.w, w3, acc[r]))));
    }
  }
  for (int j = 256; j < 259; ++j) {
    float w = nW1[j * DM + d];
#pragma unroll
    for (int r = 0; r < RB; ++r) acc[r] = fmaf(h0[r][j], w, acc[r]);
  }
  float g1 = ng1[d], be1 = nbe1[d];
#pragma unroll
  for (int r = 0; r < RB; ++r) {
    float x = acc[r];
    float s1 = waveSum(x), sq = waveSum(x * x);
    if (lane == 0) { s6[wid * 2] = s1; s6[wid * 2 + 1] = sq; }
    __syncthreads();
    float sumx = s6[0] + s6[2], sumsq = s6[1] + s6[3];
    float m = sumx * (1.0f / 128.0f);
    float var = sumsq * (1.0f / 128.0f) - m * m;
    float y = (x - m) * rsqrtf(var + EPSLN) * g1 + be1;
    hh[r][d] = fmaxf(y, 0.f);
    __syncthreads();
  }

  float acc2[RB];
#pragma unroll
  for (int r = 0; r < RB; ++r) acc2[r] = nb2[d];
  for (int j = 0; j < DM; j += 4) {
    float w0 = nW2[(j + 0) * DM + d], w1 = nW2[(j + 1) * DM + d];
    float w2 = nW2[(j + 2) * DM + d], w3 = nW2[(j + 3) * DM + d];
#pragma unroll
    for (int r = 0; r < RB; ++r) {
      float4 f = *(const float4*)&hh[r][j];
      acc2[r] = fmaf(f.x, w0, fmaf(f.y, w1, fmaf(f.z, w2, fmaf(f.w, w3, acc2[r]))));
    }
  }
  float g2 = ng2[d], be2 = nbe2[d];
  float y2[RB];
#pragma unroll
  for (int r = 0; r < RB; ++r) {
    float x = acc2[r];
    float s1 = waveSum(x), sq = waveSum(x * x);
    if (lane == 0) { s6[wid * 2] = s1; s6[wid * 2 + 1] = sq; }
    __syncthreads();
    float sumx = s6[0] + s6[2], sumsq = s6[1] + s6[3];
    float m = sumx * (1.0f / 128.0f);
    float var = sumsq * (1.0f / 128.0f) - m * m;
    float y = (x - m) * rsqrtf(var + EPSLN) * g2 + be2;
    y2[r] = fmaxf(y, 0.f);
    __syncthreads();
  }

  float w30 = nW3[d * 3 + 0], w31 = nW3[d * 3 + 1], w32 = nW3[d * 3 + 2];
#pragma unroll
  for (int r = 0; r < RB; ++r) {
    float a0 = waveSum(y2[r] * w30);
    float a1 = waveSum(y2[r] * w31);
    float a2 = waveSum(y2[r] * w32);
    if (lane == 0) { s6[wid * 3 + 0] = a0; s6[wid * 3 + 1] = a1; s6[wid * 3 + 2] = a2; }
    __syncthreads();
    if (d < 3) out[(size_t)(n0 + r) * 3 + d] = s6[d] + s6[3 + d] + nb3[d];
    __syncthreads();
  }
}

// ---------- launch ----------
extern "C" void kernel_launch(void* const* d_in, const int* in_sizes, int n_in,
                              void* d_out, int out_size, void* d_ws,
                              size_t ws_size, hipStream_t stream) {
  const float* xyz = (const float*)d_in[0];
  const float* feat = (const float*)d_in[1];
  const float* x_t = (const float*)d_in[2];
  const int* t = (const int*)d_in[3];
  const float* Wq = (const float*)d_in[4];
  const float* bq = (const float*)d_in[5];
  const float* Wk = (const float*)d_in[6];
  const float* bk = (const float*)d_in[7];
  const float* Wv = (const float*)d_in[8];
  const float* bv = (const float*)d_in[9];
  const float* Wp1 = (const float*)d_in[10];
  const float* bp1 = (const float*)d_in[11];
  const float* Wp2 = (const float*)d_in[12];
  const float* bp2 = (const float*)d_in[13];
  const float* gamma = (const float*)d_in[14];
  const float* Wproj = (const float*)d_in[15];
  const float* bproj = (const float*)d_in[16];
  const float* tW1 = (const float*)d_in[17];
  const float* tb1 = (const float*)d_in[18];
  const float* tW2 = (const float*)d_in[19];
  const float* tb2 = (const float*)d_in[20];
  const float* nW1 = (const float*)d_in[21];
  const float* nb1 = (const float*)d_in[22];
  const float* ng1 = (const float*)d_in[23];
  const float* nbe1 = (const float*)d_in[24];
  const float* nW2 = (const float*)d_in[25];
  const float* nb2 = (const float*)d_in[26];
  const float* ng2 = (const float*)d_in[27];
  const float* nbe2 = (const float*)d_in[28];
  const float* nW3 = (const float*)d_in[29];
  const float* nb3 = (const float*)d_in[30];
  float* out = (float*)d_out;

  char* ws = (char*)d_ws;
  size_t off = 0;
  int* w_idx = (int*)(ws + off); off += (size_t)ROWS * KNN * 4;
  float* w_Vf = (float*)(ws + off); off += (size_t)ROWS * DM * 4;
  float* w_qsum = (float*)(ws + off); off += (size_t)ROWS * 4;
  float* w_ksum = (float*)(ws + off); off += (size_t)ROWS * 4;
  float* w_hagg = (float*)(ws + off); off += (size_t)ROWS * DM * 4;
  float* w_vagg = (float*)(ws + off); off += (size_t)ROWS * DM * 4;
  float* w_fA = (float*)(ws + off); off += (size_t)ROWS * DM * 4;
  float* w_fB = (float*)(ws + off); off += (size_t)ROWS * DM * 4;
  float* w_temb = (float*)(ws + off); off += (size_t)B_SZ * DM * 4;
  float* w_rs = (float*)(ws + off); off += (size_t)NLAYER * 3 * DM * 4;
  float* w_ssum = (float*)(ws + off); off += (size_t)NLAYER * 4 * 4;

  knn_kernel<<<ROWS, 256, 0, stream>>>(xyz, w_idx);
  rowsum_kernel<<<NLAYER, DM, 0, stream>>>(Wq, bq, Wk, bk, Wp2, bp2, w_rs, w_ssum);

  const float* fin = feat;
  float* fout = w_fA;
  for (int l = 0; l < NLAYER; ++l) {
    const float* rsL = w_rs + (size_t)l * 3 * DM;
    const float* ssL = w_ssum + (size_t)l * 4;
    vqk_kernel<<<ROWS / RB, DM, 0, stream>>>(fin, Wv + (size_t)l * DM * DM,
                                             bv + (size_t)l * DM, rsL, ssL,
                                             w_Vf, w_qsum, w_ksum);
    attn_kernel<<<ROWS, DM, 0, stream>>>(
        xyz, w_idx, w_Vf, w_qsum, w_ksum, Wp1 + (size_t)l * 3 * DM,
        bp1 + (size_t)l * DM, rsL, ssL, w_hagg, w_vagg);
    layerout_kernel<<<ROWS / RB, DM, 0, stream>>>(
        fin, w_hagg, w_vagg, Wp2 + (size_t)l * DM * DM, bp2 + (size_t)l * DM,
        Wproj + (size_t)l * DM * DM, bproj + (size_t)l * DM, gamma, l, fout);
    fin = fout;
    fout = (fout == w_fA) ? w_fB : w_fA;
  }

  temb_kernel<<<B_SZ, DM, 0, stream>>>(t, tW1, tb1, tW2, tb2, w_temb);
  head_kernel<<<ROWS / RB, DM, 0, stream>>>(x_t, fin, w_temb, nW1, nb1, ng1,
                                            nbe1, nW2, nb2, ng2, nbe2, nW3,
                                            nb3, out);
}

// Round 3
// 278.926 us; speedup vs baseline: 1.6179x; 1.2409x over previous
//
#include <hip/hip_runtime.h>
#include <math.h>

#define B_SZ 2
#define N_PTS 2048
#define DM 128
#define KNN 128
#define NLAYER 4
#define ROWS (B_SZ * N_PTS)
#define RBV 4
#define EPSLN 1e-5f

// ---------- reductions ----------
__device__ __forceinline__ float waveSum(float v) {
#pragma unroll
  for (int o = 32; o > 0; o >>= 1) v += __shfl_xor(v, o, 64);
  return v;
}
__device__ __forceinline__ float waveMax(float v) {
#pragma unroll
  for (int o = 32; o > 0; o >>= 1) v = fmaxf(v, __shfl_xor(v, o, 64));
  return v;
}
__device__ __forceinline__ float blockSum128(float v, float* s2, int t) {
  float w = waveSum(v);
  __syncthreads();
  if ((t & 63) == 0) s2[t >> 6] = w;
  __syncthreads();
  return s2[0] + s2[1];
}
__device__ __forceinline__ unsigned waveScanIncl(unsigned v, int lane) {
#pragma unroll
  for (int o = 1; o < 64; o <<= 1) {
    unsigned u = (unsigned)__shfl_up((int)v, o, 64);
    if (lane >= o) v += u;
  }
  return v;
}

// ---------- 1. knn: radix-select K smallest, keys in registers ----------
__global__ __launch_bounds__(256) void knn_kernel(const float* __restrict__ xyz,
                                                  int* __restrict__ idx) {
  int row = blockIdx.x;
  int b = row >> 11, i = row & (N_PTS - 1);
  const float* xb = xyz + (size_t)b * N_PTS * 3;
  int tid = threadIdx.x;
  int lane = tid & 63, wid = tid >> 6;

  __shared__ unsigned hist[256];
  __shared__ unsigned wred[4];
  __shared__ unsigned sel[2];

  float xi = xb[i * 3 + 0], yi = xb[i * 3 + 1], zi = xb[i * 3 + 2];
  float sqi = xi * xi + yi * yi + zi * zi;

  float p[24];
  {
    const float4* xb4 = (const float4*)xb;
#pragma unroll
    for (int q = 0; q < 6; ++q) {
      float4 v = xb4[tid * 6 + q];
      p[q * 4 + 0] = v.x; p[q * 4 + 1] = v.y; p[q * 4 + 2] = v.z; p[q * 4 + 3] = v.w;
    }
  }
  unsigned key[8];
#pragma unroll
  for (int s = 0; s < 8; ++s) {
    float xj = p[s * 3 + 0], yj = p[s * 3 + 1], zj = p[s * 3 + 2];
    float d = sqi + xj * xj + yj * yj + zj * zj -
              2.0f * (xi * xj + yi * yj + zi * zj);
    unsigned u = __float_as_uint(d);
    key[s] = (u & 0x80000000u) ? ~u : (u | 0x80000000u);
  }

  unsigned prefix = 0;
  unsigned need = KNN;
  for (int shift = 24; shift >= 0; shift -= 8) {
    hist[tid] = 0;
    __syncthreads();
    if (shift == 24) {
#pragma unroll
      for (int s = 0; s < 8; ++s) {
        unsigned bin = key[s] >> 24;
        unsigned long long act = __ballot(1);
        while (act) {
          int src = __builtin_ctzll(act);
          unsigned bsel = (unsigned)__shfl((int)bin, src, 64);
          unsigned long long grp = __ballot(bin == bsel);
          if (lane == src)
            atomicAdd(&hist[bsel], (unsigned)__builtin_popcountll(grp));
          act &= ~grp;
        }
      }
    } else {
#pragma unroll
      for (int s = 0; s < 8; ++s) {
        unsigned k = key[s];
        if ((k >> (shift + 8)) == prefix)
          atomicAdd(&hist[(k >> shift) & 255u], 1u);
      }
    }
    __syncthreads();
    unsigned h = hist[tid];
    unsigned incl = waveScanIncl(h, lane);
    if (lane == 63) wred[wid] = incl;
    __syncthreads();
    unsigned offs = 0;
    for (int w = 0; w < wid; ++w) offs += wred[w];
    incl += offs;
    unsigned excl = incl - h;
    if (excl < need && need <= incl) { sel[0] = (unsigned)tid; sel[1] = need - excl; }
    __syncthreads();
    prefix = (prefix << 8) | sel[0];
    need = sel[1];
  }
  unsigned T = prefix;
  int need_eq = (int)need;

  unsigned clt = 0, ceq = 0;
#pragma unroll
  for (int s = 0; s < 8; ++s) {
    clt += (key[s] < T);
    ceq += (key[s] == T);
  }
  unsigned packed = clt | (ceq << 16);
  unsigned incl = waveScanIncl(packed, lane);
  if (lane == 63) wred[wid] = incl;
  __syncthreads();
  unsigned offs = 0;
  for (int w = 0; w < wid; ++w) offs += wred[w];
  unsigned totAll = wred[0] + wred[1] + wred[2] + wred[3];
  incl += offs;
  unsigned excl = incl - packed;
  int lt_base = (int)(excl & 0xFFFFu);
  int eq_base = (int)(excl >> 16);
  int total_lt = (int)(totAll & 0xFFFFu);

  int* orow = idx + (size_t)row * KNN;
  int lpos = 0, epos = 0;
#pragma unroll
  for (int s = 0; s < 8; ++s) {
    int j = tid * 8 + s;
    unsigned k = key[s];
    if (k < T) {
      orow[lt_base + lpos] = j; lpos++;
    } else if (k == T) {
      int r = eq_base + epos; epos++;
      if (r < need_eq) orow[total_lt + r] = j;
    }
  }
}

// ---------- 2. per-layer weight rowsums ----------
__global__ __launch_bounds__(128) void rowsum_kernel(
    const float* __restrict__ Wq, const float* __restrict__ bq,
    const float* __restrict__ Wk, const float* __restrict__ bk,
    const float* __restrict__ Wp2, const float* __restrict__ bp2,
    float* __restrict__ rs, float* __restrict__ ssum) {
  int l = blockIdx.x, d = threadIdx.x;
  __shared__ float s2[2];
  const float* wq = Wq + (size_t)l * DM * DM;
  const float* wk = Wk + (size_t)l * DM * DM;
  const float* wp2 = Wp2 + (size_t)l * DM * DM;
  float a = 0.f, b = 0.f, c = 0.f;
  for (int j = 0; j < DM; ++j) {
    a += wq[d * DM + j];
    b += wk[d * DM + j];
    c += wp2[d * DM + j];
  }
  rs[l * 3 * DM + d] = a;
  rs[l * 3 * DM + DM + d] = b;
  rs[l * 3 * DM + 2 * DM + d] = c;
  float sq = blockSum128(bq[l * DM + d], s2, d);
  float sk = blockSum128(bk[l * DM + d], s2, d);
  float sp = blockSum128(bp2[l * DM + d], s2, d);
  if (d == 0) { ssum[l * 4 + 0] = sq; ssum[l * 4 + 1] = sk; ssum[l * 4 + 2] = sp; }
}

// ---------- 3. V projection + q/k sums, 4 rows/block ----------
__global__ __launch_bounds__(128) void vqk_kernel(
    const float* __restrict__ feat, const float* __restrict__ Wv,
    const float* __restrict__ bv, const float* __restrict__ rs,
    const float* __restrict__ ssum, float* __restrict__ Vf,
    float* __restrict__ qsum, float* __restrict__ ksum) {
  int n0 = blockIdx.x * RBV;
  int d = threadIdx.x;
  int lane = d & 63, wid = d >> 6;
  __shared__ float fr[RBV][DM];
  __shared__ float sA[2][RBV];
  __shared__ float sB[2][RBV];
#pragma unroll
  for (int r = 0; r < RBV; ++r) fr[r][d] = feat[(size_t)(n0 + r) * DM + d];
  __syncthreads();
  float acc[RBV];
#pragma unroll
  for (int r = 0; r < RBV; ++r) acc[r] = 0.f;
  for (int j = 0; j < DM; j += 4) {
    float w0 = Wv[(j + 0) * DM + d], w1 = Wv[(j + 1) * DM + d];
    float w2 = Wv[(j + 2) * DM + d], w3 = Wv[(j + 3) * DM + d];
#pragma unroll
    for (int r = 0; r < RBV; ++r) {
      float4 f = *(const float4*)&fr[r][j];
      acc[r] = fmaf(f.x, w0, fmaf(f.y, w1, fmaf(f.z, w2, fmaf(f.w, w3, acc[r]))));
    }
  }
  float bvd = bv[d];
#pragma unroll
  for (int r = 0; r < RBV; ++r) Vf[(size_t)(n0 + r) * DM + d] = acc[r] + bvd;

  float rsq = rs[d], rsk = rs[DM + d];
#pragma unroll
  for (int r = 0; r < RBV; ++r) {
    float f = fr[r][d];
    float a = waveSum(f * rsq);
    float k = waveSum(f * rsk);
    if (lane == 0) { sA[wid][r] = a; sB[wid][r] = k; }
  }
  __syncthreads();
  if (d < RBV) qsum[n0 + d] = sA[0][d] + sA[1][d] + ssum[0];
  if (d >= 64 && d < 64 + RBV) {
    int r = d - 64;
    ksum[n0 + r] = sB[0][r] + sB[1][r] + ssum[1];
  }
}

// ---------- 4. attention: scalar-pipe weights, packed rel+attn ----------
__global__ __launch_bounds__(128) void attn_kernel(
    const float* __restrict__ xyz, const int* __restrict__ idx,
    const float* __restrict__ Vf, const float* __restrict__ qsum,
    const float* __restrict__ ksum, const float* __restrict__ Wp1,
    const float* __restrict__ bp1, const float* __restrict__ rs,
    const float* __restrict__ ssum, float* __restrict__ hagg,
    float* __restrict__ vagg) {
  int row = blockIdx.x;
  int b = row >> 11;
  int i = row & (N_PTS - 1);
  int t = threadIdx.x;

  __shared__ float4 rel4[KNN];   // (rx, ry, rz, attn)
  __shared__ int joff[KNN];      // neighbor byte offset (j*DM*4)
  __shared__ float sredA[2];
  __shared__ float sredB[2];

  const float* xb = xyz + (size_t)b * N_PTS * 3;
  float xi = xb[i * 3 + 0], yi = xb[i * 3 + 1], zi = xb[i * 3 + 2];
  int j = idx[(size_t)row * KNN + t];
  joff[t] = j * (DM * 4);
  float rx = xi - xb[j * 3 + 0];
  float ry = yi - xb[j * 3 + 1];
  float rz = zi - xb[j * 3 + 2];

  // pass1: logit via scalar-pipe (uniform) weight loads — no LDS
  const float4* W1x = (const float4*)Wp1;
  const float4* W1y = (const float4*)(Wp1 + DM);
  const float4* W1z = (const float4*)(Wp1 + 2 * DM);
  const float4* Bp = (const float4*)bp1;
  const float4* W2 = (const float4*)(rs + 2 * DM);
  float acc = 0.f;
#pragma unroll 8
  for (int q = 0; q < DM / 4; ++q) {
    float4 ax = W1x[q], ay = W1y[q], az = W1z[q], ab = Bp[q], c = W2[q];
    float h0 = fmaxf(fmaf(rx, ax.x, fmaf(ry, ay.x, fmaf(rz, az.x, ab.x))), 0.f);
    float h1 = fmaxf(fmaf(rx, ax.y, fmaf(ry, ay.y, fmaf(rz, az.y, ab.y))), 0.f);
    float h2 = fmaxf(fmaf(rx, ax.z, fmaf(ry, ay.z, fmaf(rz, az.z, ab.z))), 0.f);
    float h3 = fmaxf(fmaf(rx, ax.w, fmaf(ry, ay.w, fmaf(rz, az.w, ab.w))), 0.f);
    acc = fmaf(h0, c.x, fmaf(h1, c.y, fmaf(h2, c.z, fmaf(h3, c.w, acc))));
  }
  float logit = qsum[row] - ksum[b * N_PTS + j] + acc + ssum[2];

  // softmax over 128 threads
  float m = waveMax(logit);
  if ((t & 63) == 0) sredA[t >> 6] = m;
  __syncthreads();
  m = fmaxf(sredA[0], sredA[1]);
  float e = __expf(logit - m);
  float sw = waveSum(e);
  if ((t & 63) == 0) sredB[t >> 6] = sw;
  __syncthreads();
  float ssm = sredB[0] + sredB[1];
  rel4[t] = make_float4(rx, ry, rz, e / ssm);
  __syncthreads();

  // pass2: thread t = output dim d
  float wdx = Wp1[t], wdy = Wp1[DM + t], wdz = Wp1[2 * DM + t], wdw = bp1[t];
  const char* vb = (const char*)(Vf + ((size_t)b * N_PTS) * DM + t);
  float ha = 0.f, va = 0.f;
#pragma unroll 4
  for (int k = 0; k < KNN; ++k) {
    float4 ra = rel4[k];
    int jo = joff[k];
    float h = fmaxf(fmaf(ra.x, wdx, fmaf(ra.y, wdy, fmaf(ra.z, wdz, wdw))), 0.f);
    ha = fmaf(ra.w, h, ha);
    va = fmaf(ra.w, *(const float*)(vb + jo), va);
  }
  hagg[(size_t)row * DM + t] = ha;
  vagg[(size_t)row * DM + t] = va;
}

// ---------- 5. layer output, 4 rows/block ----------
__global__ __launch_bounds__(128) void layerout_kernel(
    const float* __restrict__ feat_in, const float* __restrict__ hagg,
    const float* __restrict__ vagg, const float* __restrict__ Wp2,
    const float* __restrict__ bp2, const float* __restrict__ Wproj,
    const float* __restrict__ bproj, const float* __restrict__ gamma, int l,
    float* __restrict__ feat_out) {
  int n0 = blockIdx.x * RBV;
  int d = threadIdx.x;
  __shared__ float hrow[RBV][DM];
  __shared__ float z[RBV][DM];
#pragma unroll
  for (int r = 0; r < RBV; ++r) hrow[r][d] = hagg[(size_t)(n0 + r) * DM + d];
  __syncthreads();
  float acc[RBV];
#pragma unroll
  for (int r = 0; r < RBV; ++r) acc[r] = 0.f;
  for (int j = 0; j < DM; j += 4) {
    float w0 = Wp2[(j + 0) * DM + d], w1 = Wp2[(j + 1) * DM + d];
    float w2 = Wp2[(j + 2) * DM + d], w3 = Wp2[(j + 3) * DM + d];
#pragma unroll
    for (int r = 0; r < RBV; ++r) {
      float4 f = *(const float4*)&hrow[r][j];
      acc[r] = fmaf(f.x, w0, fmaf(f.y, w1, fmaf(f.z, w2, fmaf(f.w, w3, acc[r]))));
    }
  }
  float bpd = bp2[d];
#pragma unroll
  for (int r = 0; r < RBV; ++r)
    z[r][d] = vagg[(size_t)(n0 + r) * DM + d] + acc[r] + bpd;
  __syncthreads();
  float acc2[RBV];
#pragma unroll
  for (int r = 0; r < RBV; ++r) acc2[r] = 0.f;
  for (int j = 0; j < DM; j += 4) {
    float w0 = Wproj[(j + 0) * DM + d], w1 = Wproj[(j + 1) * DM + d];
    float w2 = Wproj[(j + 2) * DM + d], w3 = Wproj[(j + 3) * DM + d];
#pragma unroll
    for (int r = 0; r < RBV; ++r) {
      float4 f = *(const float4*)&z[r][j];
      acc2[r] = fmaf(f.x, w0, fmaf(f.y, w1, fmaf(f.z, w2, fmaf(f.w, w3, acc2[r]))));
    }
  }
  float g = gamma[l];
  float bpr = bproj[d];
#pragma unroll
  for (int r = 0; r < RBV; ++r)
    feat_out[(size_t)(n0 + r) * DM + d] =
        feat_in[(size_t)(n0 + r) * DM + d] + g * (acc2[r] + bpr);
}

// ---------- 6. timestep embedding MLP ----------
__global__ __launch_bounds__(128) void temb_kernel(
    const int* __restrict__ t, const float* __restrict__ tW1,
    const float* __restrict__ tb1, const float* __restrict__ tW2,
    const float* __restrict__ tb2, float* __restrict__ temb) {
  int b = blockIdx.x, d = threadIdx.x;
  __shared__ float emb[DM];
  __shared__ float h1[DM];
  float tv = (float)t[b];
  float lg = logf(10000.0f);
  if (d < 64) {
    float f = expf(-lg * (float)d / 63.0f);
    emb[d] = sinf(tv * f);
  } else {
    float f = expf(-lg * (float)(d - 64) / 63.0f);
    emb[d] = cosf(tv * f);
  }
  __syncthreads();
  float acc = tb1[d];
  for (int j = 0; j < DM; ++j) acc = fmaf(emb[j], tW1[j * DM + d], acc);
  h1[d] = fmaxf(acc, 0.f);
  __syncthreads();
  float acc2 = tb2[d];
  for (int j = 0; j < DM; ++j) acc2 = fmaf(h1[j], tW2[j * DM + d], acc2);
  temb[b * DM + d] = acc2;
}

// ---------- 7. DDPM head, 4 rows/block, batched LN reductions ----------
__global__ __launch_bounds__(128) void head_kernel(
    const float* __restrict__ x_t, const float* __restrict__ fused,
    const float* __restrict__ temb, const float* __restrict__ nW1,
    const float* __restrict__ nb1, const float* __restrict__ ng1,
    const float* __restrict__ nbe1, const float* __restrict__ nW2,
    const float* __restrict__ nb2, const float* __restrict__ ng2,
    const float* __restrict__ nbe2, const float* __restrict__ nW3,
    const float* __restrict__ nb3, float* __restrict__ out) {
  int n0 = blockIdx.x * RBV;
  int d = threadIdx.x;
  int lane = d & 63, wid = d >> 6;
  __shared__ float h0[RBV][260];
  __shared__ float hh[RBV][DM];
  __shared__ float2 sred[2][RBV];
  __shared__ float sout[2][RBV][3];

#pragma unroll
  for (int r = 0; r < RBV; ++r) {
    int row = n0 + r;
    int b = row >> 11;
    h0[r][3 + d] = fused[(size_t)row * DM + d];
    h0[r][131 + d] = temb[b * DM + d];
    if (d < 3) h0[r][d] = x_t[(size_t)row * 3 + d];
    if (d == 0) h0[r][259] = 0.f;
  }
  __syncthreads();

  float acc[RBV];
#pragma unroll
  for (int r = 0; r < RBV; ++r) acc[r] = nb1[d];
  for (int j = 0; j < 256; j += 4) {
    float w0 = nW1[(j + 0) * DM + d], w1 = nW1[(j + 1) * DM + d];
    float w2 = nW1[(j + 2) * DM + d], w3 = nW1[(j + 3) * DM + d];
#pragma unroll
    for (int r = 0; r < RBV; ++r) {
      float4 f = *(const float4*)&h0[r][j];
      acc[r] = fmaf(f.x, w0, fmaf(f.y, w1, fmaf(f.z, w2, fmaf(f.w, w3, acc[r]))));
    }
  }
  for (int j = 256; j < 259; ++j) {
    float w = nW1[j * DM + d];
#pragma unroll
    for (int r = 0; r < RBV; ++r) acc[r] = fmaf(h0[r][j], w, acc[r]);
  }
  // LN1 (batched)
#pragma unroll
  for (int r = 0; r < RBV; ++r) {
    float x = acc[r];
    float s1 = waveSum(x), sq = waveSum(x * x);
    if (lane == 0) sred[wid][r] = make_float2(s1, sq);
  }
  __syncthreads();
  float g1 = ng1[d], be1 = nbe1[d];
#pragma unroll
  for (int r = 0; r < RBV; ++r) {
    float2 a = sred[0][r], b2 = sred[1][r];
    float m = (a.x + b2.x) * (1.0f / 128.0f);
    float var = (a.y + b2.y) * (1.0f / 128.0f) - m * m;
    float y = (acc[r] - m) * rsqrtf(var + EPSLN) * g1 + be1;
    hh[r][d] = fmaxf(y, 0.f);
  }
  __syncthreads();

  float acc2[RBV];
#pragma unroll
  for (int r = 0; r < RBV; ++r) acc2[r] = nb2[d];
  for (int j = 0; j < DM; j += 4) {
    float w0 = nW2[(j + 0) * DM + d], w1 = nW2[(j + 1) * DM + d];
    float w2 = nW2[(j + 2) * DM + d], w3 = nW2[(j + 3) * DM + d];
#pragma unroll
    for (int r = 0; r < RBV; ++r) {
      float4 f = *(const float4*)&hh[r][j];
      acc2[r] = fmaf(f.x, w0, fmaf(f.y, w1, fmaf(f.z, w2, fmaf(f.w, w3, acc2[r]))));
    }
  }
  // LN2 (batched)
#pragma unroll
  for (int r = 0; r < RBV; ++r) {
    float x = acc2[r];
    float s1 = waveSum(x), sq = waveSum(x * x);
    if (lane == 0) sred[wid][r] = make_float2(s1, sq);
  }
  __syncthreads();
  float g2 = ng2[d], be2 = nbe2[d];
  float y2[RBV];
#pragma unroll
  for (int r = 0; r < RBV; ++r) {
    float2 a = sred[0][r], b2 = sred[1][r];
    float m = (a.x + b2.x) * (1.0f / 128.0f);
    float var = (a.y + b2.y) * (1.0f / 128.0f) - m * m;
    float y = (acc2[r] - m) * rsqrtf(var + EPSLN) * g2 + be2;
    y2[r] = fmaxf(y, 0.f);
  }

  // final 128->3 projection (batched)
  float w30 = nW3[d * 3 + 0], w31 = nW3[d * 3 + 1], w32 = nW3[d * 3 + 2];
#pragma unroll
  for (int r = 0; r < RBV; ++r) {
    float a0 = waveSum(y2[r] * w30);
    float a1 = waveSum(y2[r] * w31);
    float a2 = waveSum(y2[r] * w32);
    if (lane == 0) {
      sout[wid][r][0] = a0; sout[wid][r][1] = a1; sout[wid][r][2] = a2;
    }
  }
  __syncthreads();
  if (d < RBV * 3) {
    int r = d / 3, c = d - r * 3;
    out[(size_t)(n0 + r) * 3 + c] = sout[0][r][c] + sout[1][r][c] + nb3[c];
  }
}

// ---------- launch ----------
extern "C" void kernel_launch(void* const* d_in, const int* in_sizes, int n_in,
                              void* d_out, int out_size, void* d_ws,
                              size_t ws_size, hipStream_t stream) {
  const float* xyz = (const float*)d_in[0];
  const float* feat = (const float*)d_in[1];
  const float* x_t = (const float*)d_in[2];
  const int* t = (const int*)d_in[3];
  const float* Wq = (const float*)d_in[4];
  const float* bq = (const float*)d_in[5];
  const float* Wk = (const float*)d_in[6];
  const float* bk = (const float*)d_in[7];
  const float* Wv = (const float*)d_in[8];
  const float* bv = (const float*)d_in[9];
  const float* Wp1 = (const float*)d_in[10];
  const float* bp1 = (const float*)d_in[11];
  const float* Wp2 = (const float*)d_in[12];
  const float* bp2 = (const float*)d_in[13];
  const float* gamma = (const float*)d_in[14];
  const float* Wproj = (const float*)d_in[15];
  const float* bproj = (const float*)d_in[16];
  const float* tW1 = (const float*)d_in[17];
  const float* tb1 = (const float*)d_in[18];
  const float* tW2 = (const float*)d_in[19];
  const float* tb2 = (const float*)d_in[20];
  const float* nW1 = (const float*)d_in[21];
  const float* nb1 = (const float*)d_in[22];
  const float* ng1 = (const float*)d_in[23];
  const float* nbe1 = (const float*)d_in[24];
  const float* nW2 = (const float*)d_in[25];
  const float* nb2 = (const float*)d_in[26];
  const float* ng2 = (const float*)d_in[27];
  const float* nbe2 = (const float*)d_in[28];
  const float* nW3 = (const float*)d_in[29];
  const float* nb3 = (const float*)d_in[30];
  float* out = (float*)d_out;

  char* ws = (char*)d_ws;
  size_t off = 0;
  int* w_idx = (int*)(ws + off); off += (size_t)ROWS * KNN * 4;
  float* w_Vf = (float*)(ws + off); off += (size_t)ROWS * DM * 4;
  float* w_qsum = (float*)(ws + off); off += (size_t)ROWS * 4;
  float* w_ksum = (float*)(ws + off); off += (size_t)ROWS * 4;
  float* w_hagg = (float*)(ws + off); off += (size_t)ROWS * DM * 4;
  float* w_vagg = (float*)(ws + off); off += (size_t)ROWS * DM * 4;
  float* w_fA = (float*)(ws + off); off += (size_t)ROWS * DM * 4;
  float* w_fB = (float*)(ws + off); off += (size_t)ROWS * DM * 4;
  float* w_temb = (float*)(ws + off); off += (size_t)B_SZ * DM * 4;
  float* w_rs = (float*)(ws + off); off += (size_t)NLAYER * 3 * DM * 4;
  float* w_ssum = (float*)(ws + off); off += (size_t)NLAYER * 4 * 4;

  knn_kernel<<<ROWS, 256, 0, stream>>>(xyz, w_idx);
  rowsum_kernel<<<NLAYER, DM, 0, stream>>>(Wq, bq, Wk, bk, Wp2, bp2, w_rs, w_ssum);

  const float* fin = feat;
  float* fout = w_fA;
  for (int l = 0; l < NLAYER; ++l) {
    const float* rsL = w_rs + (size_t)l * 3 * DM;
    const float* ssL = w_ssum + (size_t)l * 4;
    vqk_kernel<<<ROWS / RBV, DM, 0, stream>>>(fin, Wv + (size_t)l * DM * DM,
                                              bv + (size_t)l * DM, rsL, ssL,
                                              w_Vf, w_qsum, w_ksum);
    attn_kernel<<<ROWS, DM, 0, stream>>>(
        xyz, w_idx, w_Vf, w_qsum, w_ksum, Wp1 + (size_t)l * 3 * DM,
        bp1 + (size_t)l * DM, rsL, ssL, w_hagg, w_vagg);
    layerout_kernel<<<ROWS / RBV, DM, 0, stream>>>(
        fin, w_hagg, w_vagg, Wp2 + (size_t)l * DM * DM, bp2 + (size_t)l * DM,
        Wproj + (size_t)l * DM * DM, bproj + (size_t)l * DM, gamma, l, fout);
    fin = fout;
    fout = (fout == w_fA) ? w_fB : w_fA;
  }

  temb_kernel<<<B_SZ, DM, 0, stream>>>(t, tW1, tb1, tW2, tb2, w_temb);
  head_kernel<<<ROWS / RBV, DM, 0, stream>>>(x_t, fin, w_temb, nW1, nb1, ng1,
                                             nbe1, nW2, nb2, ng2, nbe2, nW3,
                                             nb3, out);
}

// Round 4
// 246.405 us; speedup vs baseline: 1.8314x; 1.1320x over previous
//
#include <hip/hip_runtime.h>
#include <math.h>

#define B_SZ 2
#define N_PTS 2048
#define DM 128
#define KNN 128
#define NLAYER 4
#define ROWS (B_SZ * N_PTS)
#define RBV 4
#define EPSLN 1e-5f

// ---------- reductions ----------
__device__ __forceinline__ float waveSum(float v) {
#pragma unroll
  for (int o = 32; o > 0; o >>= 1) v += __shfl_xor(v, o, 64);
  return v;
}
__device__ __forceinline__ float waveMax(float v) {
#pragma unroll
  for (int o = 32; o > 0; o >>= 1) v = fmaxf(v, __shfl_xor(v, o, 64));
  return v;
}
__device__ __forceinline__ float blockSum128(float v, float* s2, int t) {
  float w = waveSum(v);
  __syncthreads();
  if ((t & 63) == 0) s2[t >> 6] = w;
  __syncthreads();
  return s2[0] + s2[1];
}
__device__ __forceinline__ unsigned waveScanIncl(unsigned v, int lane) {
#pragma unroll
  for (int o = 1; o < 64; o <<= 1) {
    unsigned u = (unsigned)__shfl_up((int)v, o, 64);
    if (lane >= o) v += u;
  }
  return v;
}

// ---------- 1. knn: radix-select K smallest, keys in registers ----------
__global__ __launch_bounds__(256) void knn_kernel(const float* __restrict__ xyz,
                                                  int* __restrict__ idx) {
  int row = blockIdx.x;
  int b = row >> 11, i = row & (N_PTS - 1);
  const float* xb = xyz + (size_t)b * N_PTS * 3;
  int tid = threadIdx.x;
  int lane = tid & 63, wid = tid >> 6;

  __shared__ unsigned hist[256];
  __shared__ unsigned wred[4];
  __shared__ unsigned sel[2];

  float xi = xb[i * 3 + 0], yi = xb[i * 3 + 1], zi = xb[i * 3 + 2];
  float sqi = xi * xi + yi * yi + zi * zi;

  float p[24];
  {
    const float4* xb4 = (const float4*)xb;
#pragma unroll
    for (int q = 0; q < 6; ++q) {
      float4 v = xb4[tid * 6 + q];
      p[q * 4 + 0] = v.x; p[q * 4 + 1] = v.y; p[q * 4 + 2] = v.z; p[q * 4 + 3] = v.w;
    }
  }
  unsigned key[8];
#pragma unroll
  for (int s = 0; s < 8; ++s) {
    float xj = p[s * 3 + 0], yj = p[s * 3 + 1], zj = p[s * 3 + 2];
    float d = sqi + xj * xj + yj * yj + zj * zj -
              2.0f * (xi * xj + yi * yj + zi * zj);
    unsigned u = __float_as_uint(d);
    key[s] = (u & 0x80000000u) ? ~u : (u | 0x80000000u);
  }

  unsigned prefix = 0;
  unsigned need = KNN;
  for (int shift = 24; shift >= 0; shift -= 8) {
    hist[tid] = 0;
    __syncthreads();
    if (shift == 24) {
#pragma unroll
      for (int s = 0; s < 8; ++s) {
        unsigned bin = key[s] >> 24;
        unsigned long long act = __ballot(1);
        while (act) {
          int src = __builtin_ctzll(act);
          unsigned bsel = (unsigned)__shfl((int)bin, src, 64);
          unsigned long long grp = __ballot(bin == bsel);
          if (lane == src)
            atomicAdd(&hist[bsel], (unsigned)__builtin_popcountll(grp));
          act &= ~grp;
        }
      }
    } else {
#pragma unroll
      for (int s = 0; s < 8; ++s) {
        unsigned k = key[s];
        if ((k >> (shift + 8)) == prefix)
          atomicAdd(&hist[(k >> shift) & 255u], 1u);
      }
    }
    __syncthreads();
    unsigned h = hist[tid];
    unsigned incl = waveScanIncl(h, lane);
    if (lane == 63) wred[wid] = incl;
    __syncthreads();
    unsigned offs = 0;
    for (int w = 0; w < wid; ++w) offs += wred[w];
    incl += offs;
    unsigned excl = incl - h;
    if (excl < need && need <= incl) { sel[0] = (unsigned)tid; sel[1] = need - excl; }
    __syncthreads();
    prefix = (prefix << 8) | sel[0];
    need = sel[1];
  }
  unsigned T = prefix;
  int need_eq = (int)need;

  unsigned clt = 0, ceq = 0;
#pragma unroll
  for (int s = 0; s < 8; ++s) {
    clt += (key[s] < T);
    ceq += (key[s] == T);
  }
  unsigned packed = clt | (ceq << 16);
  unsigned incl = waveScanIncl(packed, lane);
  if (lane == 63) wred[wid] = incl;
  __syncthreads();
  unsigned offs = 0;
  for (int w = 0; w < wid; ++w) offs += wred[w];
  unsigned totAll = wred[0] + wred[1] + wred[2] + wred[3];
  incl += offs;
  unsigned excl = incl - packed;
  int lt_base = (int)(excl & 0xFFFFu);
  int eq_base = (int)(excl >> 16);
  int total_lt = (int)(totAll & 0xFFFFu);

  int* orow = idx + (size_t)row * KNN;
  int lpos = 0, epos = 0;
#pragma unroll
  for (int s = 0; s < 8; ++s) {
    int j = tid * 8 + s;
    unsigned k = key[s];
    if (k < T) {
      orow[lt_base + lpos] = j; lpos++;
    } else if (k == T) {
      int r = eq_base + epos; epos++;
      if (r < need_eq) orow[total_lt + r] = j;
    }
  }
}

// ---------- 2. per-layer weight rowsums ----------
__global__ __launch_bounds__(128) void rowsum_kernel(
    const float* __restrict__ Wq, const float* __restrict__ bq,
    const float* __restrict__ Wk, const float* __restrict__ bk,
    const float* __restrict__ Wp2, const float* __restrict__ bp2,
    float* __restrict__ rs, float* __restrict__ ssum) {
  int l = blockIdx.x, d = threadIdx.x;
  __shared__ float s2[2];
  const float* wq = Wq + (size_t)l * DM * DM;
  const float* wk = Wk + (size_t)l * DM * DM;
  const float* wp2 = Wp2 + (size_t)l * DM * DM;
  float a = 0.f, b = 0.f, c = 0.f;
  for (int j = 0; j < DM; ++j) {
    a += wq[d * DM + j];
    b += wk[d * DM + j];
    c += wp2[d * DM + j];
  }
  rs[l * 3 * DM + d] = a;
  rs[l * 3 * DM + DM + d] = b;
  rs[l * 3 * DM + 2 * DM + d] = c;
  float sq = blockSum128(bq[l * DM + d], s2, d);
  float sk = blockSum128(bk[l * DM + d], s2, d);
  float sp = blockSum128(bp2[l * DM + d], s2, d);
  if (d == 0) { ssum[l * 4 + 0] = sq; ssum[l * 4 + 1] = sk; ssum[l * 4 + 2] = sp; }
}

// ---------- 3. V projection + q/k sums, 4 rows/block, K-split x2 ----------
__global__ __launch_bounds__(256) void vqk_kernel(
    const float* __restrict__ feat, const float* __restrict__ Wv,
    const float* __restrict__ bv, const float* __restrict__ rs,
    const float* __restrict__ ssum, float* __restrict__ Vf,
    float* __restrict__ qsum, float* __restrict__ ksum) {
  int n0 = blockIdx.x * RBV;
  int t = threadIdx.x;
  int d = t & 127, half = t >> 7;
  __shared__ float fr[RBV][DM];
  __shared__ float part[RBV][DM];
  __shared__ float sA[2][RBV];
  __shared__ float sB[2][RBV];
#pragma unroll
  for (int u = 0; u < 2; ++u) {
    int r = half * 2 + u;
    fr[r][d] = feat[(size_t)(n0 + r) * DM + d];
  }
  __syncthreads();
  float acc[RBV] = {0.f, 0.f, 0.f, 0.f};
  int j0 = half * 64;
  for (int jj = 0; jj < 64; jj += 4) {
    int j = j0 + jj;
    float w0 = Wv[(j + 0) * DM + d], w1 = Wv[(j + 1) * DM + d];
    float w2 = Wv[(j + 2) * DM + d], w3 = Wv[(j + 3) * DM + d];
#pragma unroll
    for (int r = 0; r < RBV; ++r) {
      float4 f = *(const float4*)&fr[r][j];
      acc[r] = fmaf(f.x, w0, fmaf(f.y, w1, fmaf(f.z, w2, fmaf(f.w, w3, acc[r]))));
    }
  }
  if (half == 1) {
#pragma unroll
    for (int r = 0; r < RBV; ++r) part[r][d] = acc[r];
  }
  __syncthreads();
  if (half == 0) {
    float bvd = bv[d];
#pragma unroll
    for (int r = 0; r < RBV; ++r)
      Vf[(size_t)(n0 + r) * DM + d] = acc[r] + part[r][d] + bvd;
    int lane = t & 63, wid = (t >> 6) & 1;
    float rsq = rs[d], rsk = rs[DM + d];
#pragma unroll
    for (int r = 0; r < RBV; ++r) {
      float f = fr[r][d];
      float a = waveSum(f * rsq);
      float k = waveSum(f * rsk);
      if (lane == 0) { sA[wid][r] = a; sB[wid][r] = k; }
    }
  }
  __syncthreads();
  if (t < RBV) qsum[n0 + t] = sA[0][t] + sA[1][t] + ssum[0];
  if (t >= 64 && t < 64 + RBV) {
    int r = t - 64;
    ksum[n0 + r] = sB[0][r] + sB[1][r] + ssum[1];
  }
}

// ---------- 4. attention: scalar-pipe weights, 2-way accumulators ----------
__global__ __launch_bounds__(128) void attn_kernel(
    const float* __restrict__ xyz, const int* __restrict__ idx,
    const float* __restrict__ Vf, const float* __restrict__ qsum,
    const float* __restrict__ ksum, const float* __restrict__ Wp1,
    const float* __restrict__ bp1, const float* __restrict__ rs,
    const float* __restrict__ ssum, float* __restrict__ hagg,
    float* __restrict__ vagg) {
  int row = blockIdx.x;
  int b = row >> 11;
  int i = row & (N_PTS - 1);
  int t = threadIdx.x;

  __shared__ float4 rel4[KNN];   // (rx, ry, rz, attn)
  __shared__ int joff[KNN];      // neighbor byte offset (j*DM*4)
  __shared__ float sredA[2];
  __shared__ float sredB[2];

  const float* xb = xyz + (size_t)b * N_PTS * 3;
  float xi = xb[i * 3 + 0], yi = xb[i * 3 + 1], zi = xb[i * 3 + 2];
  int j = idx[(size_t)row * KNN + t];
  joff[t] = j * (DM * 4);
  float rx = xi - xb[j * 3 + 0];
  float ry = yi - xb[j * 3 + 1];
  float rz = zi - xb[j * 3 + 2];

  // pass1: logit via scalar-pipe (uniform) weight loads — no LDS, 2 accums
  const float4* W1x = (const float4*)Wp1;
  const float4* W1y = (const float4*)(Wp1 + DM);
  const float4* W1z = (const float4*)(Wp1 + 2 * DM);
  const float4* Bp = (const float4*)bp1;
  const float4* W2 = (const float4*)(rs + 2 * DM);
  float acc0 = 0.f, acc1 = 0.f;
#pragma unroll 4
  for (int q = 0; q < DM / 4; q += 2) {
    float4 ax = W1x[q], ay = W1y[q], az = W1z[q], ab = Bp[q], c = W2[q];
    float h0 = fmaxf(fmaf(rx, ax.x, fmaf(ry, ay.x, fmaf(rz, az.x, ab.x))), 0.f);
    float h1 = fmaxf(fmaf(rx, ax.y, fmaf(ry, ay.y, fmaf(rz, az.y, ab.y))), 0.f);
    float h2 = fmaxf(fmaf(rx, ax.z, fmaf(ry, ay.z, fmaf(rz, az.z, ab.z))), 0.f);
    float h3 = fmaxf(fmaf(rx, ax.w, fmaf(ry, ay.w, fmaf(rz, az.w, ab.w))), 0.f);
    acc0 = fmaf(h0, c.x, fmaf(h1, c.y, fmaf(h2, c.z, fmaf(h3, c.w, acc0))));
    float4 ax2 = W1x[q + 1], ay2 = W1y[q + 1], az2 = W1z[q + 1],
           ab2 = Bp[q + 1], c2 = W2[q + 1];
    float h4 = fmaxf(fmaf(rx, ax2.x, fmaf(ry, ay2.x, fmaf(rz, az2.x, ab2.x))), 0.f);
    float h5 = fmaxf(fmaf(rx, ax2.y, fmaf(ry, ay2.y, fmaf(rz, az2.y, ab2.y))), 0.f);
    float h6 = fmaxf(fmaf(rx, ax2.z, fmaf(ry, ay2.z, fmaf(rz, az2.z, ab2.z))), 0.f);
    float h7 = fmaxf(fmaf(rx, ax2.w, fmaf(ry, ay2.w, fmaf(rz, az2.w, ab2.w))), 0.f);
    acc1 = fmaf(h4, c2.x, fmaf(h5, c2.y, fmaf(h6, c2.z, fmaf(h7, c2.w, acc1))));
  }
  float logit = qsum[row] - ksum[b * N_PTS + j] + (acc0 + acc1) + ssum[2];

  // softmax over 128 threads
  float m = waveMax(logit);
  if ((t & 63) == 0) sredA[t >> 6] = m;
  __syncthreads();
  m = fmaxf(sredA[0], sredA[1]);
  float e = __expf(logit - m);
  float sw = waveSum(e);
  if ((t & 63) == 0) sredB[t >> 6] = sw;
  __syncthreads();
  float ssm = sredB[0] + sredB[1];
  rel4[t] = make_float4(rx, ry, rz, e / ssm);
  __syncthreads();

  // pass2: thread t = output dim d; paired iterations, split accumulators
  float wdx = Wp1[t], wdy = Wp1[DM + t], wdz = Wp1[2 * DM + t], wdw = bp1[t];
  const char* vb = (const char*)(Vf + ((size_t)b * N_PTS) * DM + t);
  float ha0 = 0.f, ha1 = 0.f, va0 = 0.f, va1 = 0.f;
#pragma unroll 4
  for (int k = 0; k < KNN; k += 2) {
    float4 ra = rel4[k];
    float4 rb = rel4[k + 1];
    int ja = joff[k], jb = joff[k + 1];
    float Va = *(const float*)(vb + ja);
    float Vb = *(const float*)(vb + jb);
    float hA = fmaxf(fmaf(ra.x, wdx, fmaf(ra.y, wdy, fmaf(ra.z, wdz, wdw))), 0.f);
    float hB = fmaxf(fmaf(rb.x, wdx, fmaf(rb.y, wdy, fmaf(rb.z, wdz, wdw))), 0.f);
    ha0 = fmaf(ra.w, hA, ha0);
    ha1 = fmaf(rb.w, hB, ha1);
    va0 = fmaf(ra.w, Va, va0);
    va1 = fmaf(rb.w, Vb, va1);
  }
  hagg[(size_t)row * DM + t] = ha0 + ha1;
  vagg[(size_t)row * DM + t] = va0 + va1;
}

// ---------- 5. layer output, 4 rows/block, K-split x2 ----------
__global__ __launch_bounds__(256) void layerout_kernel(
    const float* __restrict__ feat_in, const float* __restrict__ hagg,
    const float* __restrict__ vagg, const float* __restrict__ Wp2,
    const float* __restrict__ bp2, const float* __restrict__ Wproj,
    const float* __restrict__ bproj, const float* __restrict__ gamma, int l,
    float* __restrict__ feat_out) {
  int n0 = blockIdx.x * RBV;
  int t = threadIdx.x;
  int d = t & 127, half = t >> 7;
  __shared__ float hrow[RBV][DM];
  __shared__ float zz[RBV][DM];
  __shared__ float part[RBV][DM];
#pragma unroll
  for (int u = 0; u < 2; ++u) {
    int r = half * 2 + u;
    hrow[r][d] = hagg[(size_t)(n0 + r) * DM + d];
  }
  __syncthreads();
  float acc[RBV] = {0.f, 0.f, 0.f, 0.f};
  int j0 = half * 64;
  for (int jj = 0; jj < 64; jj += 4) {
    int j = j0 + jj;
    float w0 = Wp2[(j + 0) * DM + d], w1 = Wp2[(j + 1) * DM + d];
    float w2 = Wp2[(j + 2) * DM + d], w3 = Wp2[(j + 3) * DM + d];
#pragma unroll
    for (int r = 0; r < RBV; ++r) {
      float4 f = *(const float4*)&hrow[r][j];
      acc[r] = fmaf(f.x, w0, fmaf(f.y, w1, fmaf(f.z, w2, fmaf(f.w, w3, acc[r]))));
    }
  }
  if (half == 1) {
#pragma unroll
    for (int r = 0; r < RBV; ++r) part[r][d] = acc[r];
  }
  __syncthreads();
  if (half == 0) {
    float bpd = bp2[d];
#pragma unroll
    for (int r = 0; r < RBV; ++r)
      zz[r][d] = vagg[(size_t)(n0 + r) * DM + d] + acc[r] + part[r][d] + bpd;
  }
  __syncthreads();
  float acc2[RBV] = {0.f, 0.f, 0.f, 0.f};
  for (int jj = 0; jj < 64; jj += 4) {
    int j = j0 + jj;
    float w0 = Wproj[(j + 0) * DM + d], w1 = Wproj[(j + 1) * DM + d];
    float w2 = Wproj[(j + 2) * DM + d], w3 = Wproj[(j + 3) * DM + d];
#pragma unroll
    for (int r = 0; r < RBV; ++r) {
      float4 f = *(const float4*)&zz[r][j];
      acc2[r] = fmaf(f.x, w0, fmaf(f.y, w1, fmaf(f.z, w2, fmaf(f.w, w3, acc2[r]))));
    }
  }
  if (half == 1) {
#pragma unroll
    for (int r = 0; r < RBV; ++r) part[r][d] = acc2[r];
  }
  __syncthreads();
  if (half == 0) {
    float g = gamma[l];
    float bpr = bproj[d];
#pragma unroll
    for (int r = 0; r < RBV; ++r)
      feat_out[(size_t)(n0 + r) * DM + d] =
          feat_in[(size_t)(n0 + r) * DM + d] + g * (acc2[r] + part[r][d] + bpr);
  }
}

// ---------- 6. timestep embedding MLP ----------
__global__ __launch_bounds__(128) void temb_kernel(
    const int* __restrict__ t, const float* __restrict__ tW1,
    const float* __restrict__ tb1, const float* __restrict__ tW2,
    const float* __restrict__ tb2, float* __restrict__ temb) {
  int b = blockIdx.x, d = threadIdx.x;
  __shared__ float emb[DM];
  __shared__ float h1[DM];
  float tv = (float)t[b];
  float lg = logf(10000.0f);
  if (d < 64) {
    float f = expf(-lg * (float)d / 63.0f);
    emb[d] = sinf(tv * f);
  } else {
    float f = expf(-lg * (float)(d - 64) / 63.0f);
    emb[d] = cosf(tv * f);
  }
  __syncthreads();
  float acc = tb1[d];
  for (int j = 0; j < DM; ++j) acc = fmaf(emb[j], tW1[j * DM + d], acc);
  h1[d] = fmaxf(acc, 0.f);
  __syncthreads();
  float acc2 = tb2[d];
  for (int j = 0; j < DM; ++j) acc2 = fmaf(h1[j], tW2[j * DM + d], acc2);
  temb[b * DM + d] = acc2;
}

// ---------- 7. DDPM head, 4 rows/block, K-split x2 ----------
__global__ __launch_bounds__(256) void head_kernel(
    const float* __restrict__ x_t, const float* __restrict__ fused,
    const float* __restrict__ temb, const float* __restrict__ nW1,
    const float* __restrict__ nb1, const float* __restrict__ ng1,
    const float* __restrict__ nbe1, const float* __restrict__ nW2,
    const float* __restrict__ nb2, const float* __restrict__ ng2,
    const float* __restrict__ nbe2, const float* __restrict__ nW3,
    const float* __restrict__ nb3, float* __restrict__ out) {
  int n0 = blockIdx.x * RBV;
  int t = threadIdx.x;
  int d = t & 127, half = t >> 7;
  int lane = t & 63, wid = (t >> 6) & 1;
  __shared__ float h0[RBV][260];
  __shared__ float hh[RBV][DM];
  __shared__ float part[RBV][DM];
  __shared__ float2 sred[2][RBV];
  __shared__ float sout[2][RBV][3];

#pragma unroll
  for (int u = 0; u < 2; ++u) {
    int r = half * 2 + u;
    int row = n0 + r;
    int b = row >> 11;
    h0[r][3 + d] = fused[(size_t)row * DM + d];
    h0[r][131 + d] = temb[b * DM + d];
    if (d < 3) h0[r][d] = x_t[(size_t)row * 3 + d];
    if (d == 0) h0[r][259] = 0.f;
  }
  __syncthreads();

  // GEMV1: 259 terms; half0 j=0..127, half1 j=128..255 + 256..258
  float acc[RBV];
#pragma unroll
  for (int r = 0; r < RBV; ++r) acc[r] = half ? 0.f : nb1[d];
  int j0 = half * 128;
  for (int jj = 0; jj < 128; jj += 4) {
    int j = j0 + jj;
    float w0 = nW1[(j + 0) * DM + d], w1 = nW1[(j + 1) * DM + d];
    float w2 = nW1[(j + 2) * DM + d], w3 = nW1[(j + 3) * DM + d];
#pragma unroll
    for (int r = 0; r < RBV; ++r) {
      float4 f = *(const float4*)&h0[r][j];
      acc[r] = fmaf(f.x, w0, fmaf(f.y, w1, fmaf(f.z, w2, fmaf(f.w, w3, acc[r]))));
    }
  }
  if (half == 1) {
    for (int j = 256; j < 259; ++j) {
      float w = nW1[j * DM + d];
#pragma unroll
      for (int r = 0; r < RBV; ++r) acc[r] = fmaf(h0[r][j], w, acc[r]);
    }
#pragma unroll
    for (int r = 0; r < RBV; ++r) part[r][d] = acc[r];
  }
  __syncthreads();

  float tot[RBV];
  if (half == 0) {
#pragma unroll
    for (int r = 0; r < RBV; ++r) {
      tot[r] = acc[r] + part[r][d];
      float s1 = waveSum(tot[r]), sq = waveSum(tot[r] * tot[r]);
      if (lane == 0) sred[wid][r] = make_float2(s1, sq);
    }
  }
  __syncthreads();
  if (half == 0) {
    float g1 = ng1[d], be1 = nbe1[d];
#pragma unroll
    for (int r = 0; r < RBV; ++r) {
      float2 a = sred[0][r], b2 = sred[1][r];
      float m = (a.x + b2.x) * (1.0f / 128.0f);
      float var = (a.y + b2.y) * (1.0f / 128.0f) - m * m;
      float y = (tot[r] - m) * rsqrtf(var + EPSLN) * g1 + be1;
      hh[r][d] = fmaxf(y, 0.f);
    }
  }
  __syncthreads();

  // GEMV2: 128 terms; half j-split 64/64
  float acc2[RBV];
#pragma unroll
  for (int r = 0; r < RBV; ++r) acc2[r] = half ? 0.f : nb2[d];
  int j1 = half * 64;
  for (int jj = 0; jj < 64; jj += 4) {
    int j = j1 + jj;
    float w0 = nW2[(j + 0) * DM + d], w1 = nW2[(j + 1) * DM + d];
    float w2 = nW2[(j + 2) * DM + d], w3 = nW2[(j + 3) * DM + d];
#pragma unroll
    for (int r = 0; r < RBV; ++r) {
      float4 f = *(const float4*)&hh[r][j];
      acc2[r] = fmaf(f.x, w0, fmaf(f.y, w1, fmaf(f.z, w2, fmaf(f.w, w3, acc2[r]))));
    }
  }
  if (half == 1) {
#pragma unroll
    for (int r = 0; r < RBV; ++r) part[r][d] = acc2[r];
  }
  __syncthreads();

  if (half == 0) {
#pragma unroll
    for (int r = 0; r < RBV; ++r) {
      float x = acc2[r] + part[r][d];
      float s1 = waveSum(x), sq = waveSum(x * x);
      if (lane == 0) sred[wid][r] = make_float2(s1, sq);
      tot[r] = x;
    }
  }
  __syncthreads();
  if (half == 0) {
    float g2 = ng2[d], be2 = nbe2[d];
    float w30 = nW3[d * 3 + 0], w31 = nW3[d * 3 + 1], w32 = nW3[d * 3 + 2];
#pragma unroll
    for (int r = 0; r < RBV; ++r) {
      float2 a = sred[0][r], b2 = sred[1][r];
      float m = (a.x + b2.x) * (1.0f / 128.0f);
      float var = (a.y + b2.y) * (1.0f / 128.0f) - m * m;
      float y = (tot[r] - m) * rsqrtf(var + EPSLN) * g2 + be2;
      y = fmaxf(y, 0.f);
      float a0 = waveSum(y * w30);
      float a1 = waveSum(y * w31);
      float a2 = waveSum(y * w32);
      if (lane == 0) {
        sout[wid][r][0] = a0; sout[wid][r][1] = a1; sout[wid][r][2] = a2;
      }
    }
  }
  __syncthreads();
  if (t < RBV * 3) {
    int r = t / 3, c = t - r * 3;
    out[(size_t)(n0 + r) * 3 + c] = sout[0][r][c] + sout[1][r][c] + nb3[c];
  }
}

// ---------- launch ----------
extern "C" void kernel_launch(void* const* d_in, const int* in_sizes, int n_in,
                              void* d_out, int out_size, void* d_ws,
                              size_t ws_size, hipStream_t stream) {
  const float* xyz = (const float*)d_in[0];
  const float* feat = (const float*)d_in[1];
  const float* x_t = (const float*)d_in[2];
  const int* t = (const int*)d_in[3];
  const float* Wq = (const float*)d_in[4];
  const float* bq = (const float*)d_in[5];
  const float* Wk = (const float*)d_in[6];
  const float* bk = (const float*)d_in[7];
  const float* Wv = (const float*)d_in[8];
  const float* bv = (const float*)d_in[9];
  const float* Wp1 = (const float*)d_in[10];
  const float* bp1 = (const float*)d_in[11];
  const float* Wp2 = (const float*)d_in[12];
  const float* bp2 = (const float*)d_in[13];
  const float* gamma = (const float*)d_in[14];
  const float* Wproj = (const float*)d_in[15];
  const float* bproj = (const float*)d_in[16];
  const float* tW1 = (const float*)d_in[17];
  const float* tb1 = (const float*)d_in[18];
  const float* tW2 = (const float*)d_in[19];
  const float* tb2 = (const float*)d_in[20];
  const float* nW1 = (const float*)d_in[21];
  const float* nb1 = (const float*)d_in[22];
  const float* ng1 = (const float*)d_in[23];
  const float* nbe1 = (const float*)d_in[24];
  const float* nW2 = (const float*)d_in[25];
  const float* nb2 = (const float*)d_in[26];
  const float* ng2 = (const float*)d_in[27];
  const float* nbe2 = (const float*)d_in[28];
  const float* nW3 = (const float*)d_in[29];
  const float* nb3 = (const float*)d_in[30];
  float* out = (float*)d_out;

  char* ws = (char*)d_ws;
  size_t off = 0;
  int* w_idx = (int*)(ws + off); off += (size_t)ROWS * KNN * 4;
  float* w_Vf = (float*)(ws + off); off += (size_t)ROWS * DM * 4;
  float* w_qsum = (float*)(ws + off); off += (size_t)ROWS * 4;
  float* w_ksum = (float*)(ws + off); off += (size_t)ROWS * 4;
  float* w_hagg = (float*)(ws + off); off += (size_t)ROWS * DM * 4;
  float* w_vagg = (float*)(ws + off); off += (size_t)ROWS * DM * 4;
  float* w_fA = (float*)(ws + off); off += (size_t)ROWS * DM * 4;
  float* w_fB = (float*)(ws + off); off += (size_t)ROWS * DM * 4;
  float* w_temb = (float*)(ws + off); off += (size_t)B_SZ * DM * 4;
  float* w_rs = (float*)(ws + off); off += (size_t)NLAYER * 3 * DM * 4;
  float* w_ssum = (float*)(ws + off); off += (size_t)NLAYER * 4 * 4;

  knn_kernel<<<ROWS, 256, 0, stream>>>(xyz, w_idx);
  rowsum_kernel<<<NLAYER, DM, 0, stream>>>(Wq, bq, Wk, bk, Wp2, bp2, w_rs, w_ssum);
  temb_kernel<<<B_SZ, DM, 0, stream>>>(t, tW1, tb1, tW2, tb2, w_temb);

  const float* fin = feat;
  float* fout = w_fA;
  for (int l = 0; l < NLAYER; ++l) {
    const float* rsL = w_rs + (size_t)l * 3 * DM;
    const float* ssL = w_ssum + (size_t)l * 4;
    vqk_kernel<<<ROWS / RBV, 256, 0, stream>>>(fin, Wv + (size_t)l * DM * DM,
                                               bv + (size_t)l * DM, rsL, ssL,
                                               w_Vf, w_qsum, w_ksum);
    attn_kernel<<<ROWS, DM, 0, stream>>>(
        xyz, w_idx, w_Vf, w_qsum, w_ksum, Wp1 + (size_t)l * 3 * DM,
        bp1 + (size_t)l * DM, rsL, ssL, w_hagg, w_vagg);
    layerout_kernel<<<ROWS / RBV, 256, 0, stream>>>(
        fin, w_hagg, w_vagg, Wp2 + (size_t)l * DM * DM, bp2 + (size_t)l * DM,
        Wproj + (size_t)l * DM * DM, bproj + (size_t)l * DM, gamma, l, fout);
    fin = fout;
    fout = (fout == w_fA) ? w_fB : w_fA;
  }

  head_kernel<<<ROWS / RBV, 256, 0, stream>>>(x_t, fin, w_temb, nW1, nb1, ng1,
                                              nbe1, nW2, nb2, ng2, nbe2, nW3,
                                              nb3, out);
}